// Round 2
// baseline (402.868 us; speedup 1.0000x reference)
//
#include <hip/hip_runtime.h>
#include <math.h>

#define BB   2
#define SEQ  4096
#define DIM  512
#define NH   8
#define HD   64
#define MLPD 2048
#define ROWS (BB*SEQ)          /* 8192 */
#define SZ   (ROWS*DIM)        /* 4194304 elements */
#define EPSV 1e-5f

typedef __attribute__((ext_vector_type(8))) short bf16x8;   // A/B frag: 8 bf16
typedef __attribute__((ext_vector_type(4))) float f32x4;    // C/D frag: 4 f32

#if __has_builtin(__builtin_amdgcn_exp2f)
#define EXP2(x) __builtin_amdgcn_exp2f(x)
#else
#define EXP2(x) exp2f(x)
#endif

__device__ __forceinline__ ushort f2bf(float f) {           // RNE float->bf16
    unsigned u = __float_as_uint(f);
    u += 0x7fffu + ((u >> 16) & 1u);
    return (ushort)(u >> 16);
}
__device__ __forceinline__ unsigned pack2bf(float a, float b) {  // RNE [b:a]
    return (unsigned)f2bf(a) | ((unsigned)f2bf(b) << 16);
}
__device__ __forceinline__ unsigned pack2bf_tr(float a, float b) { // trunc [b:a], 1 op
    return (__float_as_uint(a) >> 16) | (__float_as_uint(b) & 0xffff0000u);
}

__device__ __forceinline__ void gload16(const ushort* g, ushort* l) {
    __builtin_amdgcn_global_load_lds(
        (const __attribute__((address_space(1))) unsigned*)g,
        (__attribute__((address_space(3))) unsigned*)l, 16, 0, 0);
}

// ---------------- LayerNorm -> bf16 (one block = one row of 512) ----------------
__global__ __launch_bounds__(128) void ln_kernel(const float* __restrict__ x,
        const float* __restrict__ g, const float* __restrict__ be,
        ushort* __restrict__ out)
{
    int row = blockIdx.x;
    int tid = threadIdx.x;
    const float4 v = ((const float4*)(x + (size_t)row*DIM))[tid];
    float s  = v.x + v.y + v.z + v.w;
    float ss = v.x*v.x + v.y*v.y + v.z*v.z + v.w*v.w;
    #pragma unroll
    for (int off = 32; off > 0; off >>= 1) {
        s  += __shfl_down(s,  off);
        ss += __shfl_down(ss, off);
    }
    __shared__ float red[4];
    if ((tid & 63) == 0) { red[(tid>>6)*2+0] = s; red[(tid>>6)*2+1] = ss; }
    __syncthreads();
    float sum = red[0] + red[2], sumsq = red[1] + red[3];
    float mu  = sum * (1.0f/DIM);
    float var = sumsq * (1.0f/DIM) - mu*mu;
    float rs  = rsqrtf(var + EPSV);
    float4 gv = ((const float4*)g)[tid];
    float4 bv = ((const float4*)be)[tid];
    ushort4 o;
    o.x = f2bf((v.x - mu)*rs*gv.x + bv.x);
    o.y = f2bf((v.y - mu)*rs*gv.y + bv.y);
    o.z = f2bf((v.z - mu)*rs*gv.z + bv.z);
    o.w = f2bf((v.w - mu)*rs*gv.w + bv.w);
    ((ushort4*)(out + (size_t)row*DIM))[tid] = o;
}

// ---------------- Weight transpose-convert: fp32 [K][N] -> bf16 [N][K] ----------------
__global__ __launch_bounds__(256) void wtrans_kernel(const float* __restrict__ W,
        ushort* __restrict__ Wt, int K, int N)
{
    __shared__ ushort T[64][65];
    int n0 = blockIdx.x*64, k0 = blockIdx.y*64;
    int tid = threadIdx.x;
    #pragma unroll
    for (int p = 0; p < 4; ++p) {
        int r = p*16 + (tid>>4), c = (tid&15)<<2;
        float4 w4 = *(const float4*)(W + (size_t)(k0+r)*N + n0 + c);
        T[c+0][r] = f2bf(w4.x); T[c+1][r] = f2bf(w4.y);
        T[c+2][r] = f2bf(w4.z); T[c+3][r] = f2bf(w4.w);
    }
    __syncthreads();
    #pragma unroll
    for (int p = 0; p < 4; ++p) {
        int n = p*16 + (tid>>4), k = (tid&15)<<2;
        ushort4 o; o.x = T[n][k]; o.y = T[n][k+1]; o.z = T[n][k+2]; o.w = T[n][k+3];
        *(ushort4*)(Wt + (size_t)(n0+n)*K + k0 + k) = o;
    }
}

// 4x 512x512 weights in one launch (z selects)
__global__ __launch_bounds__(256) void wtrans4_kernel(
        const float* __restrict__ W0, const float* __restrict__ W1,
        const float* __restrict__ W2, const float* __restrict__ W3,
        ushort* __restrict__ Wt)
{
    __shared__ ushort T[64][65];
    int z = blockIdx.z;
    const float* W = (z==0) ? W0 : (z==1) ? W1 : (z==2) ? W2 : W3;
    ushort* Wtz = Wt + (size_t)z*512*512;
    int n0 = blockIdx.x*64, k0 = blockIdx.y*64;
    int tid = threadIdx.x;
    #pragma unroll
    for (int p = 0; p < 4; ++p) {
        int r = p*16 + (tid>>4), c = (tid&15)<<2;
        float4 w4 = *(const float4*)(W + (size_t)(k0+r)*512 + n0 + c);
        T[c+0][r] = f2bf(w4.x); T[c+1][r] = f2bf(w4.y);
        T[c+2][r] = f2bf(w4.z); T[c+3][r] = f2bf(w4.w);
    }
    __syncthreads();
    #pragma unroll
    for (int p = 0; p < 4; ++p) {
        int n = p*16 + (tid>>4), k = (tid&15)<<2;
        ushort4 o; o.x = T[n][k]; o.y = T[n][k+1]; o.z = T[n][k+2]; o.w = T[n][k+3];
        *(ushort4*)(Wtz + (size_t)(n0+n)*512 + k0 + k) = o;
    }
}

// ---------------- bf16 MFMA GEMM, BN=64, BK=32, double-buffered (R11-proven) ----------------
// flags: 1=QKV-split 2=GELU 4=+resid 8=+bias 16=bf16 out
template<int BM, int NT>
__global__ __launch_bounds__(NT) void gemm_bf16_kernel(
        const ushort* __restrict__ A,
        const ushort* __restrict__ Wta, const ushort* __restrict__ Wtb, const ushort* __restrict__ Wtc,
        const float* __restrict__ bias, const float* __restrict__ resid,
        void* __restrict__ outv, int M, int Nn, int K, int flags)
{
    constexpr int AISS = (BM*4)/NT;      // A-tile DMA issues
    constexpr int BISS = 256/NT;         // B-tile DMA issues
    __shared__ ushort As[2][BM*32];
    __shared__ ushort Bs[2][64*32];
    int tid = threadIdx.x;
    int w = tid >> 6, lane = tid & 63, quad = lane >> 4, col = lane & 15;
    int row0 = blockIdx.y * BM, col0 = blockIdx.x * 64;
    int wm0 = w * 32;

    const ushort* Wt; int wcol0, ostride, obase_col;
    float qscale = 1.0f;
    float* outF = nullptr; ushort* outB = nullptr;
    if (flags & 1) {
        int sel = col0 >> 9;
        Wt = (sel == 0) ? Wta : ((sel == 1) ? Wtb : Wtc);
        wcol0 = col0 & 511; ostride = 512; obase_col = wcol0;
        outB = (ushort*)outv + (size_t)sel * ((size_t)M * 512);
        if (sel == 0) qscale = 0.125f * 1.44269504088896f;  // 1/sqrt(HD) * log2(e)
        flags |= 16;
    } else {
        Wt = Wta; wcol0 = col0; ostride = Nn; obase_col = col0;
        if (flags & 16) outB = (ushort*)outv; else outF = (float*)outv;
    }

    f32x4 acc[2][4];
    #pragma unroll
    for (int i = 0; i < 2; ++i)
        #pragma unroll
        for (int j = 0; j < 4; ++j) acc[i][j] = (f32x4){0.f,0.f,0.f,0.f};

    const ushort* Ag = A  + (size_t)(row0  + (tid >> 2))*K + ((tid & 3) << 3);
    const ushort* Bg = Wt + (size_t)(wcol0 + (tid >> 2))*K + ((tid & 3) << 3);

    auto issue = [&](ushort* Ad, ushort* Bd, int ko) {
        #pragma unroll
        for (int it = 0; it < AISS; ++it)
            gload16(Ag + ko + (size_t)(it*(NT/4))*K, Ad + it*NT*8 + tid*8);
        #pragma unroll
        for (int it = 0; it < BISS; ++it)
            gload16(Bg + ko + (size_t)(it*(NT/4))*K, Bd + it*NT*8 + tid*8);
    };
    auto compute = [&](const ushort* Ab, const ushort* Bb) {
        bf16x8 af[2], bfr[4];
        #pragma unroll
        for (int i = 0; i < 2; ++i)
            af[i] = *(const bf16x8*)(Ab + (wm0 + i*16 + col)*32 + quad*8);
        #pragma unroll
        for (int j = 0; j < 4; ++j)
            bfr[j] = *(const bf16x8*)(Bb + (j*16 + col)*32 + quad*8);
        #pragma unroll
        for (int i = 0; i < 2; ++i)
            #pragma unroll
            for (int j = 0; j < 4; ++j)
                acc[i][j] = __builtin_amdgcn_mfma_f32_16x16x32_bf16(af[i], bfr[j], acc[i][j], 0, 0, 0);
    };

    int niter = K >> 5;                 // K/32, always even here
    issue(As[0], Bs[0], 0);
    for (int i = 0; i < niter; i += 2) {
        __syncthreads();                              // publish buf0 (DMA drained)
        if (i + 1 < niter) issue(As[1], Bs[1], (i+1)*32);   // prefetch overlaps compute
        compute(As[0], Bs[0]);
        __syncthreads();                              // publish buf1
        if (i + 2 < niter) issue(As[0], Bs[0], (i+2)*32);
        compute(As[1], Bs[1]);
    }

    #pragma unroll
    for (int i = 0; i < 2; ++i) {
        #pragma unroll
        for (int r = 0; r < 4; ++r) {
            int row = row0 + wm0 + i*16 + quad*4 + r;
            #pragma unroll
            for (int j = 0; j < 4; ++j) {
                int oc = obase_col + j*16 + col;
                float o = acc[i][j][r] * qscale;
                if (flags & 8) o += bias[oc];
                if (flags & 2) o = 0.5f*o*(1.f + erff(o*0.70710678118654752f));
                if (flags & 4) o += resid[(size_t)row*ostride + oc];
                if (flags & 16) outB[(size_t)row*ostride + oc] = f2bf(o);
                else            outF[(size_t)row*ostride + oc] = o;
            }
        }
    }
}

// ---------------- V transpose with PV-operand key permutation ----------------
// korig = ((key'>>5)*2 + ((key'>>2)&1))*16 + ((key'>>3)&3)*4 + (key'&3).
__global__ __launch_bounds__(256) void vtrans_kernel(const ushort* __restrict__ v,
                                                     ushort* __restrict__ vt)
{
    int tt = blockIdx.x, bh = blockIdx.y;
    int b = bh >> 3, h = bh & 7;
    int tid = threadIdx.x;
    int d = tid >> 2, t0 = (tid & 3) << 4;
    ushort tmp[16];
    #pragma unroll
    for (int i = 0; i < 16; ++i) {
        int kp = t0 + i;
        int korig = ((kp>>5)*2 + ((kp>>2)&1))*16 + ((kp>>3)&3)*4 + (kp&3);
        tmp[i] = v[(size_t)(b*SEQ + tt*64 + korig)*DIM + h*HD + d];
    }
    unsigned u[8];
    #pragma unroll
    for (int j = 0; j < 8; ++j) u[j] = (unsigned)tmp[2*j] | ((unsigned)tmp[2*j+1] << 16);
    ushort* dst = vt + ((size_t)bh*HD + d)*SEQ + tt*64 + t0;
    *(uint4*)(dst)     = make_uint4(u[0],u[1],u[2],u[3]);
    *(uint4*)(dst + 8) = make_uint4(u[4],u[5],u[6],u[7]);
}

// ---------------- MFMA flash attention: direct-from-global fragments ----------------
// R14: no LDS staging, no per-iter barrier. After the R13 wave-pair split,
// every fragment a wave needs is directly loadable from global with full
// 64B-line utilization (kf: 16 rows x 64B regions; vf: 16 d-rows x 64B
// contiguous key spans). K/V fragments are register-double-buffered one
// iteration ahead (static buffer indices via x2 unroll); the compiler's
// dependence-counted vmcnt keeps the 8 prefetch loads in flight across the
// compute. LDS is used only for the one-shot kw-half combine at the end.
__global__ __launch_bounds__(256, 2) void attn_mfma_kernel(
        const ushort* __restrict__ q, const ushort* __restrict__ k,
        const ushort* __restrict__ vt, ushort* __restrict__ out)
{
    __shared__ f32x4 redA[1152];   // stride-9 slots: ot[0..1][*] + packed l
    __shared__ f32x4 redB[1152];   // ot[2..3][*]

    int qt = blockIdx.x, bh = blockIdx.y;
    int b = bh >> 3, h = bh & 7;
    int tid = threadIdx.x;
    int w = tid >> 6, lane = tid & 63;
    int quad = lane >> 4, col = lane & 15;
    int qw = w >> 1, kw = w & 1;            // pair: same q-rows, key halves
    int qn0 = qt*128 + qw*64;
    int krow0 = kw << 5;                    // this wave's 32 key rows in tile

    bf16x8 aq[4][2];    // Q^T B-operand, resident (64 q-rows per wave)
    #pragma unroll
    for (int mt = 0; mt < 4; ++mt) {
        const ushort* qp = q + (size_t)(b*SEQ + qn0 + mt*16 + col)*DIM + h*HD + quad*8;
        aq[mt][0] = *(const bf16x8*)(qp);
        aq[mt][1] = *(const bf16x8*)(qp + 32);
    }
    const short one_bf = (short)0x3F80;
    const bf16x8 ones = {one_bf,one_bf,one_bf,one_bf,one_bf,one_bf,one_bf,one_bf};
    const f32x4 zf = {0.f,0.f,0.f,0.f};

    f32x4 ot[4][4];
    f32x4 ol[4];
    #pragma unroll
    for (int mt = 0; mt < 4; ++mt) {
        ol[mt] = zf;
        #pragma unroll
        for (int t4 = 0; t4 < 4; ++t4) ot[mt][t4] = zf;
    }

    // per-lane fragment base pointers (direct global MFMA-operand layout)
    const ushort* kp0 = k  + (size_t)(b*SEQ + krow0 + col)*DIM + h*HD + quad*8;
    const ushort* vp0 = vt + ((size_t)bh*HD + col)*SEQ + krow0 + quad*8;

    auto load_frags = [&](bf16x8 (&kfb)[2][2], bf16x8 (&vfb)[4], int t) {
        const ushort* kpt = kp0 + (size_t)t*(64*DIM);
        kfb[0][0] = *(const bf16x8*)(kpt);
        kfb[0][1] = *(const bf16x8*)(kpt + 32);
        kfb[1][0] = *(const bf16x8*)(kpt + 16*DIM);
        kfb[1][1] = *(const bf16x8*)(kpt + 16*DIM + 32);
        const ushort* vpt = vp0 + t*64;
        vfb[0] = *(const bf16x8*)(vpt);
        vfb[1] = *(const bf16x8*)(vpt + 16*SEQ);
        vfb[2] = *(const bf16x8*)(vpt + 32*SEQ);
        vfb[3] = *(const bf16x8*)(vpt + 48*SEQ);
    };
    auto compute = [&](const bf16x8 (&kfb)[2][2], const bf16x8 (&vfb)[4]) {
        // S^T = K Q^T (this wave's 32 keys x 64 q)
        f32x4 sc[4][2];
        #pragma unroll
        for (int mt = 0; mt < 4; ++mt)
            #pragma unroll
            for (int kb = 0; kb < 2; ++kb) {
                sc[mt][kb] = __builtin_amdgcn_mfma_f32_16x16x32_bf16(kfb[kb][0], aq[mt][0], zf, 0, 0, 0);
                sc[mt][kb] = __builtin_amdgcn_mfma_f32_16x16x32_bf16(kfb[kb][1], aq[mt][1], sc[mt][kb], 0, 0, 0);
            }
        // P^T = exp2(S^T) truncating repack; O^T += V^T P^T ; l += 1 P^T
        union PU { bf16x8 v; uint4 u; };
        #pragma unroll
        for (int mt = 0; mt < 4; ++mt) {
            PU pb;
            pb.u.x = pack2bf_tr(EXP2(sc[mt][0][0]), EXP2(sc[mt][0][1]));
            pb.u.y = pack2bf_tr(EXP2(sc[mt][0][2]), EXP2(sc[mt][0][3]));
            pb.u.z = pack2bf_tr(EXP2(sc[mt][1][0]), EXP2(sc[mt][1][1]));
            pb.u.w = pack2bf_tr(EXP2(sc[mt][1][2]), EXP2(sc[mt][1][3]));
            #pragma unroll
            for (int t4 = 0; t4 < 4; ++t4)
                ot[mt][t4] = __builtin_amdgcn_mfma_f32_16x16x32_bf16(vfb[t4], pb.v, ot[mt][t4], 0, 0, 0);
            ol[mt] = __builtin_amdgcn_mfma_f32_16x16x32_bf16(ones, pb.v, ol[mt], 0, 0, 0);
        }
    };

    bf16x8 kfA[2][2], vfA[4], kfB[2][2], vfB[4];
    load_frags(kfA, vfA, 0);
    for (int t = 0; t < SEQ/64; t += 2) {
        if (t + 1 < SEQ/64) load_frags(kfB, vfB, t + 1);   // prefetch in flight
        compute(kfA, vfA);
        if (t + 2 < SEQ/64) load_frags(kfA, vfA, t + 2);
        compute(kfB, vfB);
    }

    // cross-wave (key-half) reduction through LDS.
    // stride 9 f32x4 = 36 words -> bank-group (lane + i) & 7, uniform.
    int rbase = ((qw << 6) + lane) * 9;
    if (kw) {
        #pragma unroll
        for (int t4 = 0; t4 < 4; ++t4) {
            redA[rbase + t4]     = ot[0][t4];
            redA[rbase + 4 + t4] = ot[1][t4];
            redB[rbase + t4]     = ot[2][t4];
            redB[rbase + 4 + t4] = ot[3][t4];
        }
        redA[rbase + 8] = (f32x4){ol[0][0], ol[1][0], ol[2][0], ol[3][0]};
    }
    __syncthreads();
    if (!kw) {
        f32x4 olp = redA[rbase + 8];
        #pragma unroll
        for (int mt = 0; mt < 4; ++mt) {
            float inv = 1.0f / (ol[mt][0] + olp[mt]);
            #pragma unroll
            for (int t4 = 0; t4 < 4; ++t4) {
                f32x4 r = (mt < 2) ? redA[rbase + mt*4 + t4]
                                   : redB[rbase + (mt-2)*4 + t4];
                f32x4 o = ot[mt][t4] + r;
                ushort4 o4;
                o4.x = f2bf(o[0] * inv);
                o4.y = f2bf(o[1] * inv);
                o4.z = f2bf(o[2] * inv);
                o4.w = f2bf(o[3] * inv);
                *(ushort4*)(out + (size_t)(b*SEQ + qn0 + mt*16 + col)*DIM + h*HD + t4*16 + quad*4) = o4;
            }
        }
    }
}

extern "C" void kernel_launch(void* const* d_in, const int* in_sizes, int n_in,
                              void* d_out, int out_size, void* d_ws, size_t ws_size,
                              hipStream_t stream)
{
    (void)in_sizes; (void)n_in; (void)out_size; (void)ws_size;
    const float* x   = (const float*)d_in[0];
    const float* Wq  = (const float*)d_in[1];
    const float* Wk  = (const float*)d_in[2];
    const float* Wv  = (const float*)d_in[3];
    const float* Wo  = (const float*)d_in[4];
    const float* bo  = (const float*)d_in[5];
    const float* W1  = (const float*)d_in[6];
    const float* b1  = (const float*)d_in[7];
    const float* W2  = (const float*)d_in[8];
    const float* b2  = (const float*)d_in[9];
    const float* g1  = (const float*)d_in[10];
    const float* be1 = (const float*)d_in[11];
    const float* g2  = (const float*)d_in[12];
    const float* be2 = (const float*)d_in[13];

    // workspace layout (ushort units)
    ushort* u = (ushort*)d_ws;
    float*  x2    = (float*)u;                       // [0, 2SZ) ushorts = SZ floats
    ushort* h     = u + 2*(size_t)SZ;                // [2SZ, 3SZ)
    ushort* qb    = u + 3*(size_t)SZ;                // [3SZ, 4SZ)
    ushort* kb    = u + 4*(size_t)SZ;
    ushort* vb    = u + 5*(size_t)SZ;
    ushort* vtb   = u + 6*(size_t)SZ;
    ushort* attnb = u + 7*(size_t)SZ;                // [7SZ, 8SZ)
    ushort* ff1   = u + 3*(size_t)SZ;                // overlays qb..vtb (dead by then), 4SZ
    ushort* wqkv  = u + 8*(size_t)SZ;                // 4x 512*512 (q,k,v,o)
    ushort* wto   = wqkv + 3*(size_t)512*512;
    ushort* wt1   = wqkv + 4*(size_t)512*512;        // [2048][512]
    ushort* wt2   = wt1  + (size_t)512*2048;         // [512][2048]
    float*  outp  = (float*)d_out;

    // weights -> bf16 transposed [N][K]
    wtrans4_kernel<<<dim3(8,8,4), 256, 0, stream>>>(Wq, Wk, Wv, Wo, wqkv);
    wtrans_kernel<<<dim3(32,8), 256, 0, stream>>>(W1, wt1, 512, 2048);
    wtrans_kernel<<<dim3(8,32), 256, 0, stream>>>(W2, wt2, 2048, 512);

    // h = LN(x) -> bf16
    ln_kernel<<<ROWS, 128, 0, stream>>>(x, g1, be1, h);
    // q,k,v = h @ {Wq,Wk,Wv} -> bf16 (q scaled by 0.125*log2e)  [R11 config]
    gemm_bf16_kernel<128,256><<<dim3(1536/64, ROWS/128), 256, 0, stream>>>(
        h, wqkv, wqkv + (size_t)512*512, wqkv + 2*(size_t)512*512,
        nullptr, nullptr, qb, ROWS, 1536, DIM, 1);
    // vt = permuted transpose(v)
    vtrans_kernel<<<dim3(SEQ/64, BB*NH), 256, 0, stream>>>(vb, vtb);
    // attn = flash(q,k,v) -> bf16
    attn_mfma_kernel<<<dim3(SEQ/128, BB*NH), 256, 0, stream>>>(qb, kb, vtb, attnb);
    // x2 = x + attn @ Wo + bo  (fp32)
    gemm_bf16_kernel<64,128><<<dim3(DIM/64, ROWS/64), 128, 0, stream>>>(
        attnb, wto, wto, wto, bo, x, x2, ROWS, DIM, DIM, 8|4);
    // h = LN(x2) -> bf16
    ln_kernel<<<ROWS, 128, 0, stream>>>(x2, g2, be2, h);
    // ff1 = gelu(h @ W1 + b1) -> bf16  [R11 config]
    gemm_bf16_kernel<128,256><<<dim3(MLPD/64, ROWS/128), 256, 0, stream>>>(
        h, wt1, wt1, wt1, b1, nullptr, ff1, ROWS, MLPD, DIM, 8|2|16);
    // out = x2 + ff1 @ W2 + b2  (fp32)
    gemm_bf16_kernel<64,128><<<dim3(DIM/64, ROWS/64), 128, 0, stream>>>(
        ff1, wt2, wt2, wt2, b2, x2, outp, ROWS, DIM, MLPD, 8|4);
}

// Round 3
// 401.875 us; speedup vs baseline: 1.0025x; 1.0025x over previous
//
#include <hip/hip_runtime.h>
#include <math.h>

#define BB   2
#define SEQ  4096
#define DIM  512
#define NH   8
#define HD   64
#define MLPD 2048
#define ROWS (BB*SEQ)          /* 8192 */
#define SZ   (ROWS*DIM)        /* 4194304 elements */
#define EPSV 1e-5f

typedef __attribute__((ext_vector_type(8))) short bf16x8;   // A/B frag: 8 bf16
typedef __attribute__((ext_vector_type(4))) float f32x4;    // C/D frag: 4 f32

#if __has_builtin(__builtin_amdgcn_exp2f)
#define EXP2(x) __builtin_amdgcn_exp2f(x)
#else
#define EXP2(x) exp2f(x)
#endif

__device__ __forceinline__ ushort f2bf(float f) {           // RNE float->bf16
    unsigned u = __float_as_uint(f);
    u += 0x7fffu + ((u >> 16) & 1u);
    return (ushort)(u >> 16);
}
__device__ __forceinline__ unsigned pack2bf(float a, float b) {  // RNE [b:a]
    return (unsigned)f2bf(a) | ((unsigned)f2bf(b) << 16);
}
__device__ __forceinline__ unsigned pack2bf_tr(float a, float b) { // trunc [b:a], 1 op
    return (__float_as_uint(a) >> 16) | (__float_as_uint(b) & 0xffff0000u);
}

__device__ __forceinline__ void gload16(const ushort* g, ushort* l) {
    __builtin_amdgcn_global_load_lds(
        (const __attribute__((address_space(1))) unsigned*)g,
        (__attribute__((address_space(3))) unsigned*)l, 16, 0, 0);
}

// ---------------- LayerNorm -> bf16 (one block = one row of 512) ----------------
__global__ __launch_bounds__(128) void ln_kernel(const float* __restrict__ x,
        const float* __restrict__ g, const float* __restrict__ be,
        ushort* __restrict__ out)
{
    int row = blockIdx.x;
    int tid = threadIdx.x;
    const float4 v = ((const float4*)(x + (size_t)row*DIM))[tid];
    float s  = v.x + v.y + v.z + v.w;
    float ss = v.x*v.x + v.y*v.y + v.z*v.z + v.w*v.w;
    #pragma unroll
    for (int off = 32; off > 0; off >>= 1) {
        s  += __shfl_down(s,  off);
        ss += __shfl_down(ss, off);
    }
    __shared__ float red[4];
    if ((tid & 63) == 0) { red[(tid>>6)*2+0] = s; red[(tid>>6)*2+1] = ss; }
    __syncthreads();
    float sum = red[0] + red[2], sumsq = red[1] + red[3];
    float mu  = sum * (1.0f/DIM);
    float var = sumsq * (1.0f/DIM) - mu*mu;
    float rs  = rsqrtf(var + EPSV);
    float4 gv = ((const float4*)g)[tid];
    float4 bv = ((const float4*)be)[tid];
    ushort4 o;
    o.x = f2bf((v.x - mu)*rs*gv.x + bv.x);
    o.y = f2bf((v.y - mu)*rs*gv.y + bv.y);
    o.z = f2bf((v.z - mu)*rs*gv.z + bv.z);
    o.w = f2bf((v.w - mu)*rs*gv.w + bv.w);
    ((ushort4*)(out + (size_t)row*DIM))[tid] = o;
}

// ---------------- Weight transpose-convert: fp32 [K][N] -> bf16 [N][K] ----------------
__global__ __launch_bounds__(256) void wtrans_kernel(const float* __restrict__ W,
        ushort* __restrict__ Wt, int K, int N)
{
    __shared__ ushort T[64][65];
    int n0 = blockIdx.x*64, k0 = blockIdx.y*64;
    int tid = threadIdx.x;
    #pragma unroll
    for (int p = 0; p < 4; ++p) {
        int r = p*16 + (tid>>4), c = (tid&15)<<2;
        float4 w4 = *(const float4*)(W + (size_t)(k0+r)*N + n0 + c);
        T[c+0][r] = f2bf(w4.x); T[c+1][r] = f2bf(w4.y);
        T[c+2][r] = f2bf(w4.z); T[c+3][r] = f2bf(w4.w);
    }
    __syncthreads();
    #pragma unroll
    for (int p = 0; p < 4; ++p) {
        int n = p*16 + (tid>>4), k = (tid&15)<<2;
        ushort4 o; o.x = T[n][k]; o.y = T[n][k+1]; o.z = T[n][k+2]; o.w = T[n][k+3];
        *(ushort4*)(Wt + (size_t)(n0+n)*K + k0 + k) = o;
    }
}

// 4x 512x512 weights in one launch (z selects)
__global__ __launch_bounds__(256) void wtrans4_kernel(
        const float* __restrict__ W0, const float* __restrict__ W1,
        const float* __restrict__ W2, const float* __restrict__ W3,
        ushort* __restrict__ Wt)
{
    __shared__ ushort T[64][65];
    int z = blockIdx.z;
    const float* W = (z==0) ? W0 : (z==1) ? W1 : (z==2) ? W2 : W3;
    ushort* Wtz = Wt + (size_t)z*512*512;
    int n0 = blockIdx.x*64, k0 = blockIdx.y*64;
    int tid = threadIdx.x;
    #pragma unroll
    for (int p = 0; p < 4; ++p) {
        int r = p*16 + (tid>>4), c = (tid&15)<<2;
        float4 w4 = *(const float4*)(W + (size_t)(k0+r)*512 + n0 + c);
        T[c+0][r] = f2bf(w4.x); T[c+1][r] = f2bf(w4.y);
        T[c+2][r] = f2bf(w4.z); T[c+3][r] = f2bf(w4.w);
    }
    __syncthreads();
    #pragma unroll
    for (int p = 0; p < 4; ++p) {
        int n = p*16 + (tid>>4), k = (tid&15)<<2;
        ushort4 o; o.x = T[n][k]; o.y = T[n][k+1]; o.z = T[n][k+2]; o.w = T[n][k+3];
        *(ushort4*)(Wtz + (size_t)(n0+n)*512 + k0 + k) = o;
    }
}

// ---------------- bf16 MFMA GEMM, BN=64, BK=32, double-buffered (R11-proven) ----------------
// flags: 1=QKV-split 2=GELU 4=+resid 8=+bias 16=bf16 out
template<int BM, int NT>
__global__ __launch_bounds__(NT) void gemm_bf16_kernel(
        const ushort* __restrict__ A,
        const ushort* __restrict__ Wta, const ushort* __restrict__ Wtb, const ushort* __restrict__ Wtc,
        const float* __restrict__ bias, const float* __restrict__ resid,
        void* __restrict__ outv, int M, int Nn, int K, int flags)
{
    constexpr int AISS = (BM*4)/NT;      // A-tile DMA issues
    constexpr int BISS = 256/NT;         // B-tile DMA issues
    __shared__ ushort As[2][BM*32];
    __shared__ ushort Bs[2][64*32];
    int tid = threadIdx.x;
    int w = tid >> 6, lane = tid & 63, quad = lane >> 4, col = lane & 15;
    int row0 = blockIdx.y * BM, col0 = blockIdx.x * 64;
    int wm0 = w * 32;

    const ushort* Wt; int wcol0, ostride, obase_col;
    float qscale = 1.0f;
    float* outF = nullptr; ushort* outB = nullptr;
    if (flags & 1) {
        int sel = col0 >> 9;
        Wt = (sel == 0) ? Wta : ((sel == 1) ? Wtb : Wtc);
        wcol0 = col0 & 511; ostride = 512; obase_col = wcol0;
        outB = (ushort*)outv + (size_t)sel * ((size_t)M * 512);
        if (sel == 0) qscale = 0.125f * 1.44269504088896f;  // 1/sqrt(HD) * log2(e)
        flags |= 16;
    } else {
        Wt = Wta; wcol0 = col0; ostride = Nn; obase_col = col0;
        if (flags & 16) outB = (ushort*)outv; else outF = (float*)outv;
    }

    f32x4 acc[2][4];
    #pragma unroll
    for (int i = 0; i < 2; ++i)
        #pragma unroll
        for (int j = 0; j < 4; ++j) acc[i][j] = (f32x4){0.f,0.f,0.f,0.f};

    const ushort* Ag = A  + (size_t)(row0  + (tid >> 2))*K + ((tid & 3) << 3);
    const ushort* Bg = Wt + (size_t)(wcol0 + (tid >> 2))*K + ((tid & 3) << 3);

    auto issue = [&](ushort* Ad, ushort* Bd, int ko) {
        #pragma unroll
        for (int it = 0; it < AISS; ++it)
            gload16(Ag + ko + (size_t)(it*(NT/4))*K, Ad + it*NT*8 + tid*8);
        #pragma unroll
        for (int it = 0; it < BISS; ++it)
            gload16(Bg + ko + (size_t)(it*(NT/4))*K, Bd + it*NT*8 + tid*8);
    };
    auto compute = [&](const ushort* Ab, const ushort* Bb) {
        bf16x8 af[2], bfr[4];
        #pragma unroll
        for (int i = 0; i < 2; ++i)
            af[i] = *(const bf16x8*)(Ab + (wm0 + i*16 + col)*32 + quad*8);
        #pragma unroll
        for (int j = 0; j < 4; ++j)
            bfr[j] = *(const bf16x8*)(Bb + (j*16 + col)*32 + quad*8);
        #pragma unroll
        for (int i = 0; i < 2; ++i)
            #pragma unroll
            for (int j = 0; j < 4; ++j)
                acc[i][j] = __builtin_amdgcn_mfma_f32_16x16x32_bf16(af[i], bfr[j], acc[i][j], 0, 0, 0);
    };

    int niter = K >> 5;                 // K/32, always even here
    issue(As[0], Bs[0], 0);
    for (int i = 0; i < niter; i += 2) {
        __syncthreads();                              // publish buf0 (DMA drained)
        if (i + 1 < niter) issue(As[1], Bs[1], (i+1)*32);   // prefetch overlaps compute
        compute(As[0], Bs[0]);
        __syncthreads();                              // publish buf1
        if (i + 2 < niter) issue(As[0], Bs[0], (i+2)*32);
        compute(As[1], Bs[1]);
    }

    #pragma unroll
    for (int i = 0; i < 2; ++i) {
        #pragma unroll
        for (int r = 0; r < 4; ++r) {
            int row = row0 + wm0 + i*16 + quad*4 + r;
            #pragma unroll
            for (int j = 0; j < 4; ++j) {
                int oc = obase_col + j*16 + col;
                float o = acc[i][j][r] * qscale;
                if (flags & 8) o += bias[oc];
                if (flags & 2) o = 0.5f*o*(1.f + erff(o*0.70710678118654752f));
                if (flags & 4) o += resid[(size_t)row*ostride + oc];
                if (flags & 16) outB[(size_t)row*ostride + oc] = f2bf(o);
                else            outF[(size_t)row*ostride + oc] = o;
            }
        }
    }
}

// ---------------- V transpose with PV-operand key permutation ----------------
// korig = ((key'>>5)*2 + ((key'>>2)&1))*16 + ((key'>>3)&3)*4 + (key'&3).
__global__ __launch_bounds__(256) void vtrans_kernel(const ushort* __restrict__ v,
                                                     ushort* __restrict__ vt)
{
    int tt = blockIdx.x, bh = blockIdx.y;
    int b = bh >> 3, h = bh & 7;
    int tid = threadIdx.x;
    int d = tid >> 2, t0 = (tid & 3) << 4;
    ushort tmp[16];
    #pragma unroll
    for (int i = 0; i < 16; ++i) {
        int kp = t0 + i;
        int korig = ((kp>>5)*2 + ((kp>>2)&1))*16 + ((kp>>3)&3)*4 + (kp&3);
        tmp[i] = v[(size_t)(b*SEQ + tt*64 + korig)*DIM + h*HD + d];
    }
    unsigned u[8];
    #pragma unroll
    for (int j = 0; j < 8; ++j) u[j] = (unsigned)tmp[2*j] | ((unsigned)tmp[2*j+1] << 16);
    ushort* dst = vt + ((size_t)bh*HD + d)*SEQ + tt*64 + t0;
    *(uint4*)(dst)     = make_uint4(u[0],u[1],u[2],u[3]);
    *(uint4*)(dst + 8) = make_uint4(u[4],u[5],u[6],u[7]);
}

// ---------------- MFMA flash attention: direct-from-global fragments ----------------
// R15: R14 dataflow (no LDS staging, no per-iter barrier; fragments loaded
// straight from global with full 64B-line utilization) + pinned scheduling.
// R14 failed because the compiler sank the prefetch loads to their use sites
// (VGPR_Count=112 proved the double-buffer was never allocated), serializing
// L2 latency every iteration. Fix: __builtin_amdgcn_sched_barrier(0) after
// each load block — loads can't sink, compute can't hoist, both buffers are
// forced live (VGPR should jump to ~180-230), and the compiler must emit a
// counted vmcnt(8) instead of a drain. s_setprio(1) wraps the MFMA clusters
// (T5). LDS only for the one-shot kw-half combine at the end.
__global__ __launch_bounds__(256, 2) void attn_mfma_kernel(
        const ushort* __restrict__ q, const ushort* __restrict__ k,
        const ushort* __restrict__ vt, ushort* __restrict__ out)
{
    __shared__ f32x4 redA[1152];   // stride-9 slots: ot[0..1][*] + packed l
    __shared__ f32x4 redB[1152];   // ot[2..3][*]

    int qt = blockIdx.x, bh = blockIdx.y;
    int b = bh >> 3, h = bh & 7;
    int tid = threadIdx.x;
    int w = tid >> 6, lane = tid & 63;
    int quad = lane >> 4, col = lane & 15;
    int qw = w >> 1, kw = w & 1;            // pair: same q-rows, key halves
    int qn0 = qt*128 + qw*64;
    int krow0 = kw << 5;                    // this wave's 32 key rows in tile

    bf16x8 aq[4][2];    // Q^T B-operand, resident (64 q-rows per wave)
    #pragma unroll
    for (int mt = 0; mt < 4; ++mt) {
        const ushort* qp = q + (size_t)(b*SEQ + qn0 + mt*16 + col)*DIM + h*HD + quad*8;
        aq[mt][0] = *(const bf16x8*)(qp);
        aq[mt][1] = *(const bf16x8*)(qp + 32);
    }
    const short one_bf = (short)0x3F80;
    const bf16x8 ones = {one_bf,one_bf,one_bf,one_bf,one_bf,one_bf,one_bf,one_bf};
    const f32x4 zf = {0.f,0.f,0.f,0.f};

    f32x4 ot[4][4];
    f32x4 ol[4];
    #pragma unroll
    for (int mt = 0; mt < 4; ++mt) {
        ol[mt] = zf;
        #pragma unroll
        for (int t4 = 0; t4 < 4; ++t4) ot[mt][t4] = zf;
    }

    // per-lane fragment base pointers (direct global MFMA-operand layout)
    const ushort* kp0 = k  + (size_t)(b*SEQ + krow0 + col)*DIM + h*HD + quad*8;
    const ushort* vp0 = vt + ((size_t)bh*HD + col)*SEQ + krow0 + quad*8;

    auto load_frags = [&](bf16x8 (&kfb)[2][2], bf16x8 (&vfb)[4], int t) {
        const ushort* kpt = kp0 + (size_t)t*(64*DIM);
        kfb[0][0] = *(const bf16x8*)(kpt);
        kfb[0][1] = *(const bf16x8*)(kpt + 32);
        kfb[1][0] = *(const bf16x8*)(kpt + 16*DIM);
        kfb[1][1] = *(const bf16x8*)(kpt + 16*DIM + 32);
        const ushort* vpt = vp0 + t*64;
        vfb[0] = *(const bf16x8*)(vpt);
        vfb[1] = *(const bf16x8*)(vpt + 16*SEQ);
        vfb[2] = *(const bf16x8*)(vpt + 32*SEQ);
        vfb[3] = *(const bf16x8*)(vpt + 48*SEQ);
    };
    auto compute = [&](const bf16x8 (&kfb)[2][2], const bf16x8 (&vfb)[4]) {
        // S^T = K Q^T (this wave's 32 keys x 64 q)
        f32x4 sc[4][2];
        __builtin_amdgcn_s_setprio(1);
        #pragma unroll
        for (int mt = 0; mt < 4; ++mt)
            #pragma unroll
            for (int kb = 0; kb < 2; ++kb) {
                sc[mt][kb] = __builtin_amdgcn_mfma_f32_16x16x32_bf16(kfb[kb][0], aq[mt][0], zf, 0, 0, 0);
                sc[mt][kb] = __builtin_amdgcn_mfma_f32_16x16x32_bf16(kfb[kb][1], aq[mt][1], sc[mt][kb], 0, 0, 0);
            }
        __builtin_amdgcn_s_setprio(0);
        // P^T = exp2(S^T) truncating repack; O^T += V^T P^T ; l += 1 P^T
        union PU { bf16x8 v; uint4 u; };
        PU pb[4];
        #pragma unroll
        for (int mt = 0; mt < 4; ++mt) {
            pb[mt].u.x = pack2bf_tr(EXP2(sc[mt][0][0]), EXP2(sc[mt][0][1]));
            pb[mt].u.y = pack2bf_tr(EXP2(sc[mt][0][2]), EXP2(sc[mt][0][3]));
            pb[mt].u.z = pack2bf_tr(EXP2(sc[mt][1][0]), EXP2(sc[mt][1][1]));
            pb[mt].u.w = pack2bf_tr(EXP2(sc[mt][1][2]), EXP2(sc[mt][1][3]));
        }
        __builtin_amdgcn_s_setprio(1);
        #pragma unroll
        for (int mt = 0; mt < 4; ++mt) {
            #pragma unroll
            for (int t4 = 0; t4 < 4; ++t4)
                ot[mt][t4] = __builtin_amdgcn_mfma_f32_16x16x32_bf16(vfb[t4], pb[mt].v, ot[mt][t4], 0, 0, 0);
            ol[mt] = __builtin_amdgcn_mfma_f32_16x16x32_bf16(ones, pb[mt].v, ol[mt], 0, 0, 0);
        }
        __builtin_amdgcn_s_setprio(0);
    };

    bf16x8 kfA[2][2], vfA[4], kfB[2][2], vfB[4];
    load_frags(kfA, vfA, 0);
    __builtin_amdgcn_sched_barrier(0);
    for (int t = 0; t < SEQ/64; t += 2) {
        if (t + 1 < SEQ/64) load_frags(kfB, vfB, t + 1);   // prefetch in flight
        __builtin_amdgcn_sched_barrier(0);                 // pin: loads stay above
        compute(kfA, vfA);
        if (t + 2 < SEQ/64) load_frags(kfA, vfA, t + 2);
        __builtin_amdgcn_sched_barrier(0);
        compute(kfB, vfB);
    }

    // cross-wave (key-half) reduction through LDS.
    // stride 9 f32x4 = 36 words -> bank-group (lane + i) & 7, uniform.
    int rbase = ((qw << 6) + lane) * 9;
    if (kw) {
        #pragma unroll
        for (int t4 = 0; t4 < 4; ++t4) {
            redA[rbase + t4]     = ot[0][t4];
            redA[rbase + 4 + t4] = ot[1][t4];
            redB[rbase + t4]     = ot[2][t4];
            redB[rbase + 4 + t4] = ot[3][t4];
        }
        redA[rbase + 8] = (f32x4){ol[0][0], ol[1][0], ol[2][0], ol[3][0]};
    }
    __syncthreads();
    if (!kw) {
        f32x4 olp = redA[rbase + 8];
        #pragma unroll
        for (int mt = 0; mt < 4; ++mt) {
            float inv = 1.0f / (ol[mt][0] + olp[mt]);
            #pragma unroll
            for (int t4 = 0; t4 < 4; ++t4) {
                f32x4 r = (mt < 2) ? redA[rbase + mt*4 + t4]
                                   : redB[rbase + (mt-2)*4 + t4];
                f32x4 o = ot[mt][t4] + r;
                ushort4 o4;
                o4.x = f2bf(o[0] * inv);
                o4.y = f2bf(o[1] * inv);
                o4.z = f2bf(o[2] * inv);
                o4.w = f2bf(o[3] * inv);
                *(ushort4*)(out + (size_t)(b*SEQ + qn0 + mt*16 + col)*DIM + h*HD + t4*16 + quad*4) = o4;
            }
        }
    }
}

extern "C" void kernel_launch(void* const* d_in, const int* in_sizes, int n_in,
                              void* d_out, int out_size, void* d_ws, size_t ws_size,
                              hipStream_t stream)
{
    (void)in_sizes; (void)n_in; (void)out_size; (void)ws_size;
    const float* x   = (const float*)d_in[0];
    const float* Wq  = (const float*)d_in[1];
    const float* Wk  = (const float*)d_in[2];
    const float* Wv  = (const float*)d_in[3];
    const float* Wo  = (const float*)d_in[4];
    const float* bo  = (const float*)d_in[5];
    const float* W1  = (const float*)d_in[6];
    const float* b1  = (const float*)d_in[7];
    const float* W2  = (const float*)d_in[8];
    const float* b2  = (const float*)d_in[9];
    const float* g1  = (const float*)d_in[10];
    const float* be1 = (const float*)d_in[11];
    const float* g2  = (const float*)d_in[12];
    const float* be2 = (const float*)d_in[13];

    // workspace layout (ushort units)
    ushort* u = (ushort*)d_ws;
    float*  x2    = (float*)u;                       // [0, 2SZ) ushorts = SZ floats
    ushort* h     = u + 2*(size_t)SZ;                // [2SZ, 3SZ)
    ushort* qb    = u + 3*(size_t)SZ;                // [3SZ, 4SZ)
    ushort* kb    = u + 4*(size_t)SZ;
    ushort* vb    = u + 5*(size_t)SZ;
    ushort* vtb   = u + 6*(size_t)SZ;
    ushort* attnb = u + 7*(size_t)SZ;                // [7SZ, 8SZ)
    ushort* ff1   = u + 3*(size_t)SZ;                // overlays qb..vtb (dead by then), 4SZ
    ushort* wqkv  = u + 8*(size_t)SZ;                // 4x 512*512 (q,k,v,o)
    ushort* wto   = wqkv + 3*(size_t)512*512;
    ushort* wt1   = wqkv + 4*(size_t)512*512;        // [2048][512]
    ushort* wt2   = wt1  + (size_t)512*2048;         // [512][2048]
    float*  outp  = (float*)d_out;

    // weights -> bf16 transposed [N][K]
    wtrans4_kernel<<<dim3(8,8,4), 256, 0, stream>>>(Wq, Wk, Wv, Wo, wqkv);
    wtrans_kernel<<<dim3(32,8), 256, 0, stream>>>(W1, wt1, 512, 2048);
    wtrans_kernel<<<dim3(8,32), 256, 0, stream>>>(W2, wt2, 2048, 512);

    // h = LN(x) -> bf16
    ln_kernel<<<ROWS, 128, 0, stream>>>(x, g1, be1, h);
    // q,k,v = h @ {Wq,Wk,Wv} -> bf16 (q scaled by 0.125*log2e)  [R11 config]
    gemm_bf16_kernel<128,256><<<dim3(1536/64, ROWS/128), 256, 0, stream>>>(
        h, wqkv, wqkv + (size_t)512*512, wqkv + 2*(size_t)512*512,
        nullptr, nullptr, qb, ROWS, 1536, DIM, 1);
    // vt = permuted transpose(v)
    vtrans_kernel<<<dim3(SEQ/64, BB*NH), 256, 0, stream>>>(vb, vtb);
    // attn = flash(q,k,v) -> bf16
    attn_mfma_kernel<<<dim3(SEQ/128, BB*NH), 256, 0, stream>>>(qb, kb, vtb, attnb);
    // x2 = x + attn @ Wo + bo  (fp32)
    gemm_bf16_kernel<64,128><<<dim3(DIM/64, ROWS/64), 128, 0, stream>>>(
        attnb, wto, wto, wto, bo, x, x2, ROWS, DIM, DIM, 8|4);
    // h = LN(x2) -> bf16
    ln_kernel<<<ROWS, 128, 0, stream>>>(x2, g2, be2, h);
    // ff1 = gelu(h @ W1 + b1) -> bf16  [R11 config]
    gemm_bf16_kernel<128,256><<<dim3(MLPD/64, ROWS/128), 256, 0, stream>>>(
        h, wt1, wt1, wt1, b1, nullptr, ff1, ROWS, MLPD, DIM, 8|2|16);
    // out = x2 + ff1 @ W2 + b2  (fp32)
    gemm_bf16_kernel<64,128><<<dim3(DIM/64, ROWS/64), 128, 0, stream>>>(
        ff1, wt2, wt2, wt2, b2, x2, outp, ROWS, DIM, MLPD, 8|4);
}

// Round 4
// 401.172 us; speedup vs baseline: 1.0042x; 1.0018x over previous
//
#include <hip/hip_runtime.h>
#include <math.h>

#define BB   2
#define SEQ  4096
#define DIM  512
#define NH   8
#define HD   64
#define MLPD 2048
#define ROWS (BB*SEQ)          /* 8192 */
#define SZ   (ROWS*DIM)        /* 4194304 elements */
#define EPSV 1e-5f

typedef __attribute__((ext_vector_type(8))) short bf16x8;   // A/B frag: 8 bf16
typedef __attribute__((ext_vector_type(4))) float f32x4;    // C/D frag: 4 f32

#if __has_builtin(__builtin_amdgcn_exp2f)
#define EXP2(x) __builtin_amdgcn_exp2f(x)
#else
#define EXP2(x) exp2f(x)
#endif

__device__ __forceinline__ ushort f2bf(float f) {           // RNE float->bf16
    unsigned u = __float_as_uint(f);
    u += 0x7fffu + ((u >> 16) & 1u);
    return (ushort)(u >> 16);
}
__device__ __forceinline__ unsigned pack2bf(float a, float b) {  // RNE [b:a]
    return (unsigned)f2bf(a) | ((unsigned)f2bf(b) << 16);
}
__device__ __forceinline__ unsigned pack2bf_tr(float a, float b) { // trunc [b:a], 1 op
    return (__float_as_uint(a) >> 16) | (__float_as_uint(b) & 0xffff0000u);
}

__device__ __forceinline__ void gload16(const ushort* g, ushort* l) {
    __builtin_amdgcn_global_load_lds(
        (const __attribute__((address_space(1))) unsigned*)g,
        (__attribute__((address_space(3))) unsigned*)l, 16, 0, 0);
}

// ---------------- LayerNorm -> bf16 (one block = one row of 512) ----------------
__global__ __launch_bounds__(128) void ln_kernel(const float* __restrict__ x,
        const float* __restrict__ g, const float* __restrict__ be,
        ushort* __restrict__ out)
{
    int row = blockIdx.x;
    int tid = threadIdx.x;
    const float4 v = ((const float4*)(x + (size_t)row*DIM))[tid];
    float s  = v.x + v.y + v.z + v.w;
    float ss = v.x*v.x + v.y*v.y + v.z*v.z + v.w*v.w;
    #pragma unroll
    for (int off = 32; off > 0; off >>= 1) {
        s  += __shfl_down(s,  off);
        ss += __shfl_down(ss, off);
    }
    __shared__ float red[4];
    if ((tid & 63) == 0) { red[(tid>>6)*2+0] = s; red[(tid>>6)*2+1] = ss; }
    __syncthreads();
    float sum = red[0] + red[2], sumsq = red[1] + red[3];
    float mu  = sum * (1.0f/DIM);
    float var = sumsq * (1.0f/DIM) - mu*mu;
    float rs  = rsqrtf(var + EPSV);
    float4 gv = ((const float4*)g)[tid];
    float4 bv = ((const float4*)be)[tid];
    ushort4 o;
    o.x = f2bf((v.x - mu)*rs*gv.x + bv.x);
    o.y = f2bf((v.y - mu)*rs*gv.y + bv.y);
    o.z = f2bf((v.z - mu)*rs*gv.z + bv.z);
    o.w = f2bf((v.w - mu)*rs*gv.w + bv.w);
    ((ushort4*)(out + (size_t)row*DIM))[tid] = o;
}

// ---------------- Weight transpose-convert: fp32 [K][N] -> bf16 [N][K] ----------------
__global__ __launch_bounds__(256) void wtrans_kernel(const float* __restrict__ W,
        ushort* __restrict__ Wt, int K, int N)
{
    __shared__ ushort T[64][65];
    int n0 = blockIdx.x*64, k0 = blockIdx.y*64;
    int tid = threadIdx.x;
    #pragma unroll
    for (int p = 0; p < 4; ++p) {
        int r = p*16 + (tid>>4), c = (tid&15)<<2;
        float4 w4 = *(const float4*)(W + (size_t)(k0+r)*N + n0 + c);
        T[c+0][r] = f2bf(w4.x); T[c+1][r] = f2bf(w4.y);
        T[c+2][r] = f2bf(w4.z); T[c+3][r] = f2bf(w4.w);
    }
    __syncthreads();
    #pragma unroll
    for (int p = 0; p < 4; ++p) {
        int n = p*16 + (tid>>4), k = (tid&15)<<2;
        ushort4 o; o.x = T[n][k]; o.y = T[n][k+1]; o.z = T[n][k+2]; o.w = T[n][k+3];
        *(ushort4*)(Wt + (size_t)(n0+n)*K + k0 + k) = o;
    }
}

// 4x 512x512 weights in one launch (z selects)
__global__ __launch_bounds__(256) void wtrans4_kernel(
        const float* __restrict__ W0, const float* __restrict__ W1,
        const float* __restrict__ W2, const float* __restrict__ W3,
        ushort* __restrict__ Wt)
{
    __shared__ ushort T[64][65];
    int z = blockIdx.z;
    const float* W = (z==0) ? W0 : (z==1) ? W1 : (z==2) ? W2 : W3;
    ushort* Wtz = Wt + (size_t)z*512*512;
    int n0 = blockIdx.x*64, k0 = blockIdx.y*64;
    int tid = threadIdx.x;
    #pragma unroll
    for (int p = 0; p < 4; ++p) {
        int r = p*16 + (tid>>4), c = (tid&15)<<2;
        float4 w4 = *(const float4*)(W + (size_t)(k0+r)*512 + n0 + c);
        T[c+0][r] = f2bf(w4.x); T[c+1][r] = f2bf(w4.y);
        T[c+2][r] = f2bf(w4.z); T[c+3][r] = f2bf(w4.w);
    }
    __syncthreads();
    #pragma unroll
    for (int p = 0; p < 4; ++p) {
        int n = p*16 + (tid>>4), k = (tid&15)<<2;
        ushort4 o; o.x = T[n][k]; o.y = T[n][k+1]; o.z = T[n][k+2]; o.w = T[n][k+3];
        *(ushort4*)(Wtz + (size_t)(n0+n)*512 + k0 + k) = o;
    }
}

// ---------------- bf16 MFMA GEMM, BN=64, BK=32, double-buffered (R11-proven) ----------------
// flags: 1=QKV-split 2=GELU 4=+resid 8=+bias 16=bf16 out
template<int BM, int NT>
__global__ __launch_bounds__(NT) void gemm_bf16_kernel(
        const ushort* __restrict__ A,
        const ushort* __restrict__ Wta, const ushort* __restrict__ Wtb, const ushort* __restrict__ Wtc,
        const float* __restrict__ bias, const float* __restrict__ resid,
        void* __restrict__ outv, int M, int Nn, int K, int flags)
{
    constexpr int AISS = (BM*4)/NT;      // A-tile DMA issues
    constexpr int BISS = 256/NT;         // B-tile DMA issues
    __shared__ ushort As[2][BM*32];
    __shared__ ushort Bs[2][64*32];
    int tid = threadIdx.x;
    int w = tid >> 6, lane = tid & 63, quad = lane >> 4, col = lane & 15;
    int row0 = blockIdx.y * BM, col0 = blockIdx.x * 64;
    int wm0 = w * 32;

    const ushort* Wt; int wcol0, ostride, obase_col;
    float qscale = 1.0f;
    float* outF = nullptr; ushort* outB = nullptr;
    if (flags & 1) {
        int sel = col0 >> 9;
        Wt = (sel == 0) ? Wta : ((sel == 1) ? Wtb : Wtc);
        wcol0 = col0 & 511; ostride = 512; obase_col = wcol0;
        outB = (ushort*)outv + (size_t)sel * ((size_t)M * 512);
        if (sel == 0) qscale = 0.125f * 1.44269504088896f;  // 1/sqrt(HD) * log2(e)
        flags |= 16;
    } else {
        Wt = Wta; wcol0 = col0; ostride = Nn; obase_col = col0;
        if (flags & 16) outB = (ushort*)outv; else outF = (float*)outv;
    }

    f32x4 acc[2][4];
    #pragma unroll
    for (int i = 0; i < 2; ++i)
        #pragma unroll
        for (int j = 0; j < 4; ++j) acc[i][j] = (f32x4){0.f,0.f,0.f,0.f};

    const ushort* Ag = A  + (size_t)(row0  + (tid >> 2))*K + ((tid & 3) << 3);
    const ushort* Bg = Wt + (size_t)(wcol0 + (tid >> 2))*K + ((tid & 3) << 3);

    auto issue = [&](ushort* Ad, ushort* Bd, int ko) {
        #pragma unroll
        for (int it = 0; it < AISS; ++it)
            gload16(Ag + ko + (size_t)(it*(NT/4))*K, Ad + it*NT*8 + tid*8);
        #pragma unroll
        for (int it = 0; it < BISS; ++it)
            gload16(Bg + ko + (size_t)(it*(NT/4))*K, Bd + it*NT*8 + tid*8);
    };
    auto compute = [&](const ushort* Ab, const ushort* Bb) {
        bf16x8 af[2], bfr[4];
        #pragma unroll
        for (int i = 0; i < 2; ++i)
            af[i] = *(const bf16x8*)(Ab + (wm0 + i*16 + col)*32 + quad*8);
        #pragma unroll
        for (int j = 0; j < 4; ++j)
            bfr[j] = *(const bf16x8*)(Bb + (j*16 + col)*32 + quad*8);
        #pragma unroll
        for (int i = 0; i < 2; ++i)
            #pragma unroll
            for (int j = 0; j < 4; ++j)
                acc[i][j] = __builtin_amdgcn_mfma_f32_16x16x32_bf16(af[i], bfr[j], acc[i][j], 0, 0, 0);
    };

    int niter = K >> 5;                 // K/32, always even here
    issue(As[0], Bs[0], 0);
    for (int i = 0; i < niter; i += 2) {
        __syncthreads();                              // publish buf0 (DMA drained)
        if (i + 1 < niter) issue(As[1], Bs[1], (i+1)*32);   // prefetch overlaps compute
        compute(As[0], Bs[0]);
        __syncthreads();                              // publish buf1
        if (i + 2 < niter) issue(As[0], Bs[0], (i+2)*32);
        compute(As[1], Bs[1]);
    }

    #pragma unroll
    for (int i = 0; i < 2; ++i) {
        #pragma unroll
        for (int r = 0; r < 4; ++r) {
            int row = row0 + wm0 + i*16 + quad*4 + r;
            #pragma unroll
            for (int j = 0; j < 4; ++j) {
                int oc = obase_col + j*16 + col;
                float o = acc[i][j][r] * qscale;
                if (flags & 8) o += bias[oc];
                if (flags & 2) o = 0.5f*o*(1.f + erff(o*0.70710678118654752f));
                if (flags & 4) o += resid[(size_t)row*ostride + oc];
                if (flags & 16) outB[(size_t)row*ostride + oc] = f2bf(o);
                else            outF[(size_t)row*ostride + oc] = o;
            }
        }
    }
}

// ---------------- V transpose with PV-operand key permutation ----------------
// korig = ((key'>>5)*2 + ((key'>>2)&1))*16 + ((key'>>3)&3)*4 + (key'&3).
__global__ __launch_bounds__(256) void vtrans_kernel(const ushort* __restrict__ v,
                                                     ushort* __restrict__ vt)
{
    int tt = blockIdx.x, bh = blockIdx.y;
    int b = bh >> 3, h = bh & 7;
    int tid = threadIdx.x;
    int d = tid >> 2, t0 = (tid & 3) << 4;
    ushort tmp[16];
    #pragma unroll
    for (int i = 0; i < 16; ++i) {
        int kp = t0 + i;
        int korig = ((kp>>5)*2 + ((kp>>2)&1))*16 + ((kp>>3)&3)*4 + (kp&3);
        tmp[i] = v[(size_t)(b*SEQ + tt*64 + korig)*DIM + h*HD + d];
    }
    unsigned u[8];
    #pragma unroll
    for (int j = 0; j < 8; ++j) u[j] = (unsigned)tmp[2*j] | ((unsigned)tmp[2*j+1] << 16);
    ushort* dst = vt + ((size_t)bh*HD + d)*SEQ + tt*64 + t0;
    *(uint4*)(dst)     = make_uint4(u[0],u[1],u[2],u[3]);
    *(uint4*)(dst + 8) = make_uint4(u[4],u[5],u[6],u[7]);
}

// ---------------- MFMA flash attention: direct-from-global fragments ----------------
// R16: R15 dataflow + XCD-aware (qt,bh) swizzle. R14/R15 were L3-BW-bound at
// ~7.5-8 TB/s: consecutive blockIdx round-robin across XCDs scattered the 32
// qt-blocks sharing one bh's K/V over all 8 XCDs, so per-XCD L2 (4 MiB)
// thrashed (~64 distinct 1MB working sets) and 1 GB/dispatch streamed from
// Infinity Cache. Remap so XCD i serves only bh {2i, 2i+1}: K/V (2 MB) stays
// L2-resident; demand at the MFMA floor is 46 B/cyc/CU = 82% of L2 ceiling.
// Mapping is bijective -> correctness never depends on the dispatch heuristic.
__global__ __launch_bounds__(256, 2) void attn_mfma_kernel(
        const ushort* __restrict__ q, const ushort* __restrict__ k,
        const ushort* __restrict__ vt, ushort* __restrict__ out)
{
    __shared__ f32x4 redA[1152];   // stride-9 slots: ot[0..1][*] + packed l
    __shared__ f32x4 redB[1152];   // ot[2..3][*]

    // XCD-aware swizzle: flat HW id -> (xcd, slot) -> each XCD owns 2 heads.
    int flat = blockIdx.x + (blockIdx.y << 5);     // gridDim = (32, 16)
    int xcd  = flat & 7, slot = flat >> 3;         // dispatch round-robins % 8
    int bh   = (xcd << 1) | (slot >> 5);
    int qt   = slot & 31;
    int b = bh >> 3, h = bh & 7;
    int tid = threadIdx.x;
    int w = tid >> 6, lane = tid & 63;
    int quad = lane >> 4, col = lane & 15;
    int qw = w >> 1, kw = w & 1;            // pair: same q-rows, key halves
    int qn0 = qt*128 + qw*64;
    int krow0 = kw << 5;                    // this wave's 32 key rows in tile

    bf16x8 aq[4][2];    // Q^T B-operand, resident (64 q-rows per wave)
    #pragma unroll
    for (int mt = 0; mt < 4; ++mt) {
        const ushort* qp = q + (size_t)(b*SEQ + qn0 + mt*16 + col)*DIM + h*HD + quad*8;
        aq[mt][0] = *(const bf16x8*)(qp);
        aq[mt][1] = *(const bf16x8*)(qp + 32);
    }
    const short one_bf = (short)0x3F80;
    const bf16x8 ones = {one_bf,one_bf,one_bf,one_bf,one_bf,one_bf,one_bf,one_bf};
    const f32x4 zf = {0.f,0.f,0.f,0.f};

    f32x4 ot[4][4];
    f32x4 ol[4];
    #pragma unroll
    for (int mt = 0; mt < 4; ++mt) {
        ol[mt] = zf;
        #pragma unroll
        for (int t4 = 0; t4 < 4; ++t4) ot[mt][t4] = zf;
    }

    // per-lane fragment base pointers (direct global MFMA-operand layout)
    const ushort* kp0 = k  + (size_t)(b*SEQ + krow0 + col)*DIM + h*HD + quad*8;
    const ushort* vp0 = vt + ((size_t)bh*HD + col)*SEQ + krow0 + quad*8;

    auto load_frags = [&](bf16x8 (&kfb)[2][2], bf16x8 (&vfb)[4], int t) {
        const ushort* kpt = kp0 + (size_t)t*(64*DIM);
        kfb[0][0] = *(const bf16x8*)(kpt);
        kfb[0][1] = *(const bf16x8*)(kpt + 32);
        kfb[1][0] = *(const bf16x8*)(kpt + 16*DIM);
        kfb[1][1] = *(const bf16x8*)(kpt + 16*DIM + 32);
        const ushort* vpt = vp0 + t*64;
        vfb[0] = *(const bf16x8*)(vpt);
        vfb[1] = *(const bf16x8*)(vpt + 16*SEQ);
        vfb[2] = *(const bf16x8*)(vpt + 32*SEQ);
        vfb[3] = *(const bf16x8*)(vpt + 48*SEQ);
    };
    auto compute = [&](const bf16x8 (&kfb)[2][2], const bf16x8 (&vfb)[4]) {
        // S^T = K Q^T (this wave's 32 keys x 64 q)
        f32x4 sc[4][2];
        __builtin_amdgcn_s_setprio(1);
        #pragma unroll
        for (int mt = 0; mt < 4; ++mt)
            #pragma unroll
            for (int kb = 0; kb < 2; ++kb) {
                sc[mt][kb] = __builtin_amdgcn_mfma_f32_16x16x32_bf16(kfb[kb][0], aq[mt][0], zf, 0, 0, 0);
                sc[mt][kb] = __builtin_amdgcn_mfma_f32_16x16x32_bf16(kfb[kb][1], aq[mt][1], sc[mt][kb], 0, 0, 0);
            }
        __builtin_amdgcn_s_setprio(0);
        // P^T = exp2(S^T) truncating repack; O^T += V^T P^T ; l += 1 P^T
        union PU { bf16x8 v; uint4 u; };
        PU pb[4];
        #pragma unroll
        for (int mt = 0; mt < 4; ++mt) {
            pb[mt].u.x = pack2bf_tr(EXP2(sc[mt][0][0]), EXP2(sc[mt][0][1]));
            pb[mt].u.y = pack2bf_tr(EXP2(sc[mt][0][2]), EXP2(sc[mt][0][3]));
            pb[mt].u.z = pack2bf_tr(EXP2(sc[mt][1][0]), EXP2(sc[mt][1][1]));
            pb[mt].u.w = pack2bf_tr(EXP2(sc[mt][1][2]), EXP2(sc[mt][1][3]));
        }
        __builtin_amdgcn_s_setprio(1);
        #pragma unroll
        for (int mt = 0; mt < 4; ++mt) {
            #pragma unroll
            for (int t4 = 0; t4 < 4; ++t4)
                ot[mt][t4] = __builtin_amdgcn_mfma_f32_16x16x32_bf16(vfb[t4], pb[mt].v, ot[mt][t4], 0, 0, 0);
            ol[mt] = __builtin_amdgcn_mfma_f32_16x16x32_bf16(ones, pb[mt].v, ol[mt], 0, 0, 0);
        }
        __builtin_amdgcn_s_setprio(0);
    };

    bf16x8 kfA[2][2], vfA[4], kfB[2][2], vfB[4];
    load_frags(kfA, vfA, 0);
    __builtin_amdgcn_sched_barrier(0);
    for (int t = 0; t < SEQ/64; t += 2) {
        if (t + 1 < SEQ/64) load_frags(kfB, vfB, t + 1);   // prefetch in flight
        __builtin_amdgcn_sched_barrier(0);                 // pin: loads stay above
        compute(kfA, vfA);
        if (t + 2 < SEQ/64) load_frags(kfA, vfA, t + 2);
        __builtin_amdgcn_sched_barrier(0);
        compute(kfB, vfB);
    }

    // cross-wave (key-half) reduction through LDS.
    // stride 9 f32x4 = 36 words -> bank-group (lane + i) & 7, uniform.
    int rbase = ((qw << 6) + lane) * 9;
    if (kw) {
        #pragma unroll
        for (int t4 = 0; t4 < 4; ++t4) {
            redA[rbase + t4]     = ot[0][t4];
            redA[rbase + 4 + t4] = ot[1][t4];
            redB[rbase + t4]     = ot[2][t4];
            redB[rbase + 4 + t4] = ot[3][t4];
        }
        redA[rbase + 8] = (f32x4){ol[0][0], ol[1][0], ol[2][0], ol[3][0]};
    }
    __syncthreads();
    if (!kw) {
        f32x4 olp = redA[rbase + 8];
        #pragma unroll
        for (int mt = 0; mt < 4; ++mt) {
            float inv = 1.0f / (ol[mt][0] + olp[mt]);
            #pragma unroll
            for (int t4 = 0; t4 < 4; ++t4) {
                f32x4 r = (mt < 2) ? redA[rbase + mt*4 + t4]
                                   : redB[rbase + (mt-2)*4 + t4];
                f32x4 o = ot[mt][t4] + r;
                ushort4 o4;
                o4.x = f2bf(o[0] * inv);
                o4.y = f2bf(o[1] * inv);
                o4.z = f2bf(o[2] * inv);
                o4.w = f2bf(o[3] * inv);
                *(ushort4*)(out + (size_t)(b*SEQ + qn0 + mt*16 + col)*DIM + h*HD + t4*16 + quad*4) = o4;
            }
        }
    }
}

extern "C" void kernel_launch(void* const* d_in, const int* in_sizes, int n_in,
                              void* d_out, int out_size, void* d_ws, size_t ws_size,
                              hipStream_t stream)
{
    (void)in_sizes; (void)n_in; (void)out_size; (void)ws_size;
    const float* x   = (const float*)d_in[0];
    const float* Wq  = (const float*)d_in[1];
    const float* Wk  = (const float*)d_in[2];
    const float* Wv  = (const float*)d_in[3];
    const float* Wo  = (const float*)d_in[4];
    const float* bo  = (const float*)d_in[5];
    const float* W1  = (const float*)d_in[6];
    const float* b1  = (const float*)d_in[7];
    const float* W2  = (const float*)d_in[8];
    const float* b2  = (const float*)d_in[9];
    const float* g1  = (const float*)d_in[10];
    const float* be1 = (const float*)d_in[11];
    const float* g2  = (const float*)d_in[12];
    const float* be2 = (const float*)d_in[13];

    // workspace layout (ushort units)
    ushort* u = (ushort*)d_ws;
    float*  x2    = (float*)u;                       // [0, 2SZ) ushorts = SZ floats
    ushort* h     = u + 2*(size_t)SZ;                // [2SZ, 3SZ)
    ushort* qb    = u + 3*(size_t)SZ;                // [3SZ, 4SZ)
    ushort* kb    = u + 4*(size_t)SZ;
    ushort* vb    = u + 5*(size_t)SZ;
    ushort* vtb   = u + 6*(size_t)SZ;
    ushort* attnb = u + 7*(size_t)SZ;                // [7SZ, 8SZ)
    ushort* ff1   = u + 3*(size_t)SZ;                // overlays qb..vtb (dead by then), 4SZ
    ushort* wqkv  = u + 8*(size_t)SZ;                // 4x 512*512 (q,k,v,o)
    ushort* wto   = wqkv + 3*(size_t)512*512;
    ushort* wt1   = wqkv + 4*(size_t)512*512;        // [2048][512]
    ushort* wt2   = wt1  + (size_t)512*2048;         // [512][2048]
    float*  outp  = (float*)d_out;

    // weights -> bf16 transposed [N][K]
    wtrans4_kernel<<<dim3(8,8,4), 256, 0, stream>>>(Wq, Wk, Wv, Wo, wqkv);
    wtrans_kernel<<<dim3(32,8), 256, 0, stream>>>(W1, wt1, 512, 2048);
    wtrans_kernel<<<dim3(8,32), 256, 0, stream>>>(W2, wt2, 2048, 512);

    // h = LN(x) -> bf16
    ln_kernel<<<ROWS, 128, 0, stream>>>(x, g1, be1, h);
    // q,k,v = h @ {Wq,Wk,Wv} -> bf16 (q scaled by 0.125*log2e)  [R11 config]
    gemm_bf16_kernel<128,256><<<dim3(1536/64, ROWS/128), 256, 0, stream>>>(
        h, wqkv, wqkv + (size_t)512*512, wqkv + 2*(size_t)512*512,
        nullptr, nullptr, qb, ROWS, 1536, DIM, 1);
    // vt = permuted transpose(v)
    vtrans_kernel<<<dim3(SEQ/64, BB*NH), 256, 0, stream>>>(vb, vtb);
    // attn = flash(q,k,v) -> bf16
    attn_mfma_kernel<<<dim3(SEQ/128, BB*NH), 256, 0, stream>>>(qb, kb, vtb, attnb);
    // x2 = x + attn @ Wo + bo  (fp32)
    gemm_bf16_kernel<64,128><<<dim3(DIM/64, ROWS/64), 128, 0, stream>>>(
        attnb, wto, wto, wto, bo, x, x2, ROWS, DIM, DIM, 8|4);
    // h = LN(x2) -> bf16
    ln_kernel<<<ROWS, 128, 0, stream>>>(x2, g2, be2, h);
    // ff1 = gelu(h @ W1 + b1) -> bf16  [R11 config]
    gemm_bf16_kernel<128,256><<<dim3(MLPD/64, ROWS/128), 256, 0, stream>>>(
        h, wt1, wt1, wt1, b1, nullptr, ff1, ROWS, MLPD, DIM, 8|2|16);
    // out = x2 + ff1 @ W2 + b2  (fp32)
    gemm_bf16_kernel<64,128><<<dim3(DIM/64, ROWS/64), 128, 0, stream>>>(
        ff1, wt2, wt2, wt2, b2, x2, outp, ROWS, DIM, MLPD, 8|4);
}

// Round 5
// 349.910 us; speedup vs baseline: 1.1513x; 1.1465x over previous
//
#include <hip/hip_runtime.h>
#include <math.h>

#define BB   2
#define SEQ  4096
#define DIM  512
#define NH   8
#define HD   64
#define MLPD 2048
#define ROWS (BB*SEQ)          /* 8192 */
#define SZ   (ROWS*DIM)        /* 4194304 elements */
#define EPSV 1e-5f

typedef __attribute__((ext_vector_type(8))) short bf16x8;   // A/B frag: 8 bf16
typedef __attribute__((ext_vector_type(4))) float f32x4;    // C/D frag: 4 f32

#if __has_builtin(__builtin_amdgcn_exp2f)
#define EXP2(x) __builtin_amdgcn_exp2f(x)
#else
#define EXP2(x) exp2f(x)
#endif

__device__ __forceinline__ ushort f2bf(float f) {           // RNE float->bf16
    unsigned u = __float_as_uint(f);
    u += 0x7fffu + ((u >> 16) & 1u);
    return (ushort)(u >> 16);
}
__device__ __forceinline__ unsigned pack2bf(float a, float b) {  // RNE [b:a]
    return (unsigned)f2bf(a) | ((unsigned)f2bf(b) << 16);
}
__device__ __forceinline__ unsigned pack2bf_tr(float a, float b) { // trunc [b:a], 1 op
    return (__float_as_uint(a) >> 16) | (__float_as_uint(b) & 0xffff0000u);
}

__device__ __forceinline__ void gload16(const ushort* g, ushort* l) {
    __builtin_amdgcn_global_load_lds(
        (const __attribute__((address_space(1))) unsigned*)g,
        (__attribute__((address_space(3))) unsigned*)l, 16, 0, 0);
}

// ---------------- LayerNorm -> bf16 (one block = one row of 512) ----------------
__global__ __launch_bounds__(128) void ln_kernel(const float* __restrict__ x,
        const float* __restrict__ g, const float* __restrict__ be,
        ushort* __restrict__ out)
{
    int row = blockIdx.x;
    int tid = threadIdx.x;
    const float4 v = ((const float4*)(x + (size_t)row*DIM))[tid];
    float s  = v.x + v.y + v.z + v.w;
    float ss = v.x*v.x + v.y*v.y + v.z*v.z + v.w*v.w;
    #pragma unroll
    for (int off = 32; off > 0; off >>= 1) {
        s  += __shfl_down(s,  off);
        ss += __shfl_down(ss, off);
    }
    __shared__ float red[4];
    if ((tid & 63) == 0) { red[(tid>>6)*2+0] = s; red[(tid>>6)*2+1] = ss; }
    __syncthreads();
    float sum = red[0] + red[2], sumsq = red[1] + red[3];
    float mu  = sum * (1.0f/DIM);
    float var = sumsq * (1.0f/DIM) - mu*mu;
    float rs  = rsqrtf(var + EPSV);
    float4 gv = ((const float4*)g)[tid];
    float4 bv = ((const float4*)be)[tid];
    ushort4 o;
    o.x = f2bf((v.x - mu)*rs*gv.x + bv.x);
    o.y = f2bf((v.y - mu)*rs*gv.y + bv.y);
    o.z = f2bf((v.z - mu)*rs*gv.z + bv.z);
    o.w = f2bf((v.w - mu)*rs*gv.w + bv.w);
    ((ushort4*)(out + (size_t)row*DIM))[tid] = o;
}

// ---------------- Weight transpose-convert: fp32 [K][N] -> bf16 [N][K] ----------------
__global__ __launch_bounds__(256) void wtrans_kernel(const float* __restrict__ W,
        ushort* __restrict__ Wt, int K, int N)
{
    __shared__ ushort T[64][65];
    int n0 = blockIdx.x*64, k0 = blockIdx.y*64;
    int tid = threadIdx.x;
    #pragma unroll
    for (int p = 0; p < 4; ++p) {
        int r = p*16 + (tid>>4), c = (tid&15)<<2;
        float4 w4 = *(const float4*)(W + (size_t)(k0+r)*N + n0 + c);
        T[c+0][r] = f2bf(w4.x); T[c+1][r] = f2bf(w4.y);
        T[c+2][r] = f2bf(w4.z); T[c+3][r] = f2bf(w4.w);
    }
    __syncthreads();
    #pragma unroll
    for (int p = 0; p < 4; ++p) {
        int n = p*16 + (tid>>4), k = (tid&15)<<2;
        ushort4 o; o.x = T[n][k]; o.y = T[n][k+1]; o.z = T[n][k+2]; o.w = T[n][k+3];
        *(ushort4*)(Wt + (size_t)(n0+n)*K + k0 + k) = o;
    }
}

// 4x 512x512 weights in one launch (z selects)
__global__ __launch_bounds__(256) void wtrans4_kernel(
        const float* __restrict__ W0, const float* __restrict__ W1,
        const float* __restrict__ W2, const float* __restrict__ W3,
        ushort* __restrict__ Wt)
{
    __shared__ ushort T[64][65];
    int z = blockIdx.z;
    const float* W = (z==0) ? W0 : (z==1) ? W1 : (z==2) ? W2 : W3;
    ushort* Wtz = Wt + (size_t)z*512*512;
    int n0 = blockIdx.x*64, k0 = blockIdx.y*64;
    int tid = threadIdx.x;
    #pragma unroll
    for (int p = 0; p < 4; ++p) {
        int r = p*16 + (tid>>4), c = (tid&15)<<2;
        float4 w4 = *(const float4*)(W + (size_t)(k0+r)*512 + n0 + c);
        T[c+0][r] = f2bf(w4.x); T[c+1][r] = f2bf(w4.y);
        T[c+2][r] = f2bf(w4.z); T[c+3][r] = f2bf(w4.w);
    }
    __syncthreads();
    #pragma unroll
    for (int p = 0; p < 4; ++p) {
        int n = p*16 + (tid>>4), k = (tid&15)<<2;
        ushort4 o; o.x = T[n][k]; o.y = T[n][k+1]; o.z = T[n][k+2]; o.w = T[n][k+3];
        *(ushort4*)(Wtz + (size_t)(n0+n)*512 + k0 + k) = o;
    }
}

// ---------------- bf16 MFMA GEMM, BN=64, BK=32, double-buffered (R11-proven) ----------------
// flags: 1=QKV-split 2=GELU 4=+resid 8=+bias 16=bf16 out
template<int BM, int NT>
__global__ __launch_bounds__(NT) void gemm_bf16_kernel(
        const ushort* __restrict__ A,
        const ushort* __restrict__ Wta, const ushort* __restrict__ Wtb, const ushort* __restrict__ Wtc,
        const float* __restrict__ bias, const float* __restrict__ resid,
        void* __restrict__ outv, int M, int Nn, int K, int flags)
{
    constexpr int AISS = (BM*4)/NT;      // A-tile DMA issues
    constexpr int BISS = 256/NT;         // B-tile DMA issues
    __shared__ ushort As[2][BM*32];
    __shared__ ushort Bs[2][64*32];
    int tid = threadIdx.x;
    int w = tid >> 6, lane = tid & 63, quad = lane >> 4, col = lane & 15;
    int row0 = blockIdx.y * BM, col0 = blockIdx.x * 64;
    int wm0 = w * 32;

    const ushort* Wt; int wcol0, ostride, obase_col;
    float qscale = 1.0f;
    float* outF = nullptr; ushort* outB = nullptr;
    if (flags & 1) {
        int sel = col0 >> 9;
        Wt = (sel == 0) ? Wta : ((sel == 1) ? Wtb : Wtc);
        wcol0 = col0 & 511; ostride = 512; obase_col = wcol0;
        outB = (ushort*)outv + (size_t)sel * ((size_t)M * 512);
        if (sel == 0) qscale = 0.125f * 1.44269504088896f;  // 1/sqrt(HD) * log2(e)
        flags |= 16;
    } else {
        Wt = Wta; wcol0 = col0; ostride = Nn; obase_col = col0;
        if (flags & 16) outB = (ushort*)outv; else outF = (float*)outv;
    }

    f32x4 acc[2][4];
    #pragma unroll
    for (int i = 0; i < 2; ++i)
        #pragma unroll
        for (int j = 0; j < 4; ++j) acc[i][j] = (f32x4){0.f,0.f,0.f,0.f};

    const ushort* Ag = A  + (size_t)(row0  + (tid >> 2))*K + ((tid & 3) << 3);
    const ushort* Bg = Wt + (size_t)(wcol0 + (tid >> 2))*K + ((tid & 3) << 3);

    auto issue = [&](ushort* Ad, ushort* Bd, int ko) {
        #pragma unroll
        for (int it = 0; it < AISS; ++it)
            gload16(Ag + ko + (size_t)(it*(NT/4))*K, Ad + it*NT*8 + tid*8);
        #pragma unroll
        for (int it = 0; it < BISS; ++it)
            gload16(Bg + ko + (size_t)(it*(NT/4))*K, Bd + it*NT*8 + tid*8);
    };
    auto compute = [&](const ushort* Ab, const ushort* Bb) {
        bf16x8 af[2], bfr[4];
        #pragma unroll
        for (int i = 0; i < 2; ++i)
            af[i] = *(const bf16x8*)(Ab + (wm0 + i*16 + col)*32 + quad*8);
        #pragma unroll
        for (int j = 0; j < 4; ++j)
            bfr[j] = *(const bf16x8*)(Bb + (j*16 + col)*32 + quad*8);
        #pragma unroll
        for (int i = 0; i < 2; ++i)
            #pragma unroll
            for (int j = 0; j < 4; ++j)
                acc[i][j] = __builtin_amdgcn_mfma_f32_16x16x32_bf16(af[i], bfr[j], acc[i][j], 0, 0, 0);
    };

    int niter = K >> 5;                 // K/32, always even here
    issue(As[0], Bs[0], 0);
    for (int i = 0; i < niter; i += 2) {
        __syncthreads();                              // publish buf0 (DMA drained)
        if (i + 1 < niter) issue(As[1], Bs[1], (i+1)*32);   // prefetch overlaps compute
        compute(As[0], Bs[0]);
        __syncthreads();                              // publish buf1
        if (i + 2 < niter) issue(As[0], Bs[0], (i+2)*32);
        compute(As[1], Bs[1]);
    }

    #pragma unroll
    for (int i = 0; i < 2; ++i) {
        #pragma unroll
        for (int r = 0; r < 4; ++r) {
            int row = row0 + wm0 + i*16 + quad*4 + r;
            #pragma unroll
            for (int j = 0; j < 4; ++j) {
                int oc = obase_col + j*16 + col;
                float o = acc[i][j][r] * qscale;
                if (flags & 8) o += bias[oc];
                if (flags & 2) o = 0.5f*o*(1.f + erff(o*0.70710678118654752f));
                if (flags & 4) o += resid[(size_t)row*ostride + oc];
                if (flags & 16) outB[(size_t)row*ostride + oc] = f2bf(o);
                else            outF[(size_t)row*ostride + oc] = o;
            }
        }
    }
}

// ---------------- V transpose with PV-operand key permutation ----------------
// korig = ((key'>>5)*2 + ((key'>>2)&1))*16 + ((key'>>3)&3)*4 + (key'&3).
__global__ __launch_bounds__(256) void vtrans_kernel(const ushort* __restrict__ v,
                                                     ushort* __restrict__ vt)
{
    int tt = blockIdx.x, bh = blockIdx.y;
    int b = bh >> 3, h = bh & 7;
    int tid = threadIdx.x;
    int d = tid >> 2, t0 = (tid & 3) << 4;
    ushort tmp[16];
    #pragma unroll
    for (int i = 0; i < 16; ++i) {
        int kp = t0 + i;
        int korig = ((kp>>5)*2 + ((kp>>2)&1))*16 + ((kp>>3)&3)*4 + (kp&3);
        tmp[i] = v[(size_t)(b*SEQ + tt*64 + korig)*DIM + h*HD + d];
    }
    unsigned u[8];
    #pragma unroll
    for (int j = 0; j < 8; ++j) u[j] = (unsigned)tmp[2*j] | ((unsigned)tmp[2*j+1] << 16);
    ushort* dst = vt + ((size_t)bh*HD + d)*SEQ + tt*64 + t0;
    *(uint4*)(dst)     = make_uint4(u[0],u[1],u[2],u[3]);
    *(uint4*)(dst + 8) = make_uint4(u[4],u[5],u[6],u[7]);
}

// ---------------- MFMA flash attention: LDS-staged + XCD swizzle ----------------
// R17 = R13 structure (LDS staging reads each K/V line ONCE per block — the
// direct-from-global R14-16 variants hammered L2 with ~128 redundant reads
// per line and plateaued at 134us regardless of locality) + R16's XCD swizzle
// (proven by FETCH 70MB->12MB: K/V stays L2-resident, so R13's 6.5TB/s L3
// staging cap is gone) + overlap levers: all 8 ds_read_b128 hoisted to the
// top of the iteration (vf's lgkmcnt retires under QK/exp2) and setprio(1)
// around the MFMA clusters (T5).
__global__ __launch_bounds__(256, 2) void attn_mfma_kernel(
        const ushort* __restrict__ q, const ushort* __restrict__ k,
        const ushort* __restrict__ vt, ushort* __restrict__ out)
{
    __shared__ __align__(16) ushort Kt[2][64][72];
    __shared__ __align__(16) ushort Vt[2][64][72];

    // XCD-aware swizzle (R16-proven): each XCD serves only bh {2i,2i+1}.
    int flat = blockIdx.x + (blockIdx.y << 5);     // gridDim = (32, 16)
    int xcd  = flat & 7, slot = flat >> 3;         // dispatch round-robins % 8
    int bh   = (xcd << 1) | (slot >> 5);
    int qt   = slot & 31;
    int b = bh >> 3, h = bh & 7;
    int tid = threadIdx.x;
    int w = tid >> 6, lane = tid & 63;
    int quad = lane >> 4, col = lane & 15;
    int qw = w >> 1, kw = w & 1;            // pair: same q-rows, key halves
    int qn0 = qt*128 + qw*64;
    int krow0 = kw << 5;                    // this wave's 32 key rows in tile

    bf16x8 aq[4][2];    // Q^T B-operand, resident (64 q-rows per wave)
    #pragma unroll
    for (int mt = 0; mt < 4; ++mt) {
        const ushort* qp = q + (size_t)(b*SEQ + qn0 + mt*16 + col)*DIM + h*HD + quad*8;
        aq[mt][0] = *(const bf16x8*)(qp);
        aq[mt][1] = *(const bf16x8*)(qp + 32);
    }
    const short one_bf = (short)0x3F80;
    const bf16x8 ones = {one_bf,one_bf,one_bf,one_bf,one_bf,one_bf,one_bf,one_bf};
    const f32x4 zf = {0.f,0.f,0.f,0.f};

    f32x4 ot[4][4];
    f32x4 ol[4];
    #pragma unroll
    for (int mt = 0; mt < 4; ++mt) {
        ol[mt] = zf;
        #pragma unroll
        for (int t4 = 0; t4 < 4; ++t4) ot[mt][t4] = zf;
    }

    int skey = tid >> 2, sd0 = (tid & 3) << 4;
    bf16x8 kr[2], vr[2];
    auto load_tile = [&](int t) {
        const ushort* kp = k + (size_t)(b*SEQ + t*64 + skey)*DIM + h*HD + sd0;
        kr[0] = *(const bf16x8*)(kp);
        kr[1] = *(const bf16x8*)(kp + 8);
        const ushort* vp = vt + ((size_t)bh*HD + skey)*SEQ + t*64 + sd0;
        vr[0] = *(const bf16x8*)(vp);
        vr[1] = *(const bf16x8*)(vp + 8);
    };
    auto store_tile = [&](int p) {
        *(bf16x8*)&Kt[p][skey][sd0]     = kr[0];
        *(bf16x8*)&Kt[p][skey][sd0+8]   = kr[1];
        *(bf16x8*)&Vt[p][skey][sd0]     = vr[0];
        *(bf16x8*)&Vt[p][skey][sd0+8]   = vr[1];
    };

    load_tile(0);
    store_tile(0);
    __syncthreads();

    for (int t = 0; t < SEQ/64; ++t) {
        int p = t & 1;
        if (t + 1 < SEQ/64) load_tile(t + 1);     // VMEM in flight over compute

        // hoist ALL LDS fragment reads: kf feeds QK now, vf retires under QK/exp2
        bf16x8 kf0[2], kf1[2], vf[4];
        #pragma unroll
        for (int kb = 0; kb < 2; ++kb) {
            const ushort* kbp = &Kt[p][krow0 + kb*16 + col][quad*8];
            kf0[kb] = *(const bf16x8*)(kbp);
            kf1[kb] = *(const bf16x8*)(kbp + 32);
        }
        #pragma unroll
        for (int t4 = 0; t4 < 4; ++t4)
            vf[t4] = *(const bf16x8*)&Vt[p][t4*16 + col][krow0 + quad*8];

        // S^T = K Q^T (this wave's 32 keys x 64 q)
        f32x4 sc[4][2];
        __builtin_amdgcn_s_setprio(1);
        #pragma unroll
        for (int mt = 0; mt < 4; ++mt)
            #pragma unroll
            for (int kb = 0; kb < 2; ++kb) {
                sc[mt][kb] = __builtin_amdgcn_mfma_f32_16x16x32_bf16(kf0[kb], aq[mt][0], zf, 0, 0, 0);
                sc[mt][kb] = __builtin_amdgcn_mfma_f32_16x16x32_bf16(kf1[kb], aq[mt][1], sc[mt][kb], 0, 0, 0);
            }
        __builtin_amdgcn_s_setprio(0);

        // P^T = exp2(S^T), in-register repack (truncating, 1 op per pair)
        union PU { bf16x8 v; uint4 u; };
        PU pb[4];
        #pragma unroll
        for (int mt = 0; mt < 4; ++mt) {
            pb[mt].u.x = pack2bf_tr(EXP2(sc[mt][0][0]), EXP2(sc[mt][0][1]));
            pb[mt].u.y = pack2bf_tr(EXP2(sc[mt][0][2]), EXP2(sc[mt][0][3]));
            pb[mt].u.z = pack2bf_tr(EXP2(sc[mt][1][0]), EXP2(sc[mt][1][1]));
            pb[mt].u.w = pack2bf_tr(EXP2(sc[mt][1][2]), EXP2(sc[mt][1][3]));
        }

        // O^T += V^T P^T over this wave's key chunk ; l += 1 P^T
        __builtin_amdgcn_s_setprio(1);
        #pragma unroll
        for (int mt = 0; mt < 4; ++mt) {
            #pragma unroll
            for (int t4 = 0; t4 < 4; ++t4)
                ot[mt][t4] = __builtin_amdgcn_mfma_f32_16x16x32_bf16(vf[t4], pb[mt].v, ot[mt][t4], 0, 0, 0);
            ol[mt] = __builtin_amdgcn_mfma_f32_16x16x32_bf16(ones, pb[mt].v, ol[mt], 0, 0, 0);
        }
        __builtin_amdgcn_s_setprio(0);

        if (t + 1 < SEQ/64) store_tile(p ^ 1);    // tile t-1 fully consumed pre-barrier
        __syncthreads();
    }

    // cross-wave (key-half) reduction through the dead K/V buffers.
    // stride 9 f32x4 = 36 words -> bank-group (lane + i) & 7, uniform.
    f32x4* redA = (f32x4*)Kt;   // 1152 slots: ot[0][*], ot[1][*], packed l
    f32x4* redB = (f32x4*)Vt;   // stride 9 too: ot[2][*], ot[3][*]
    int rbase = ((qw << 6) + lane) * 9;
    if (kw) {
        #pragma unroll
        for (int t4 = 0; t4 < 4; ++t4) {
            redA[rbase + t4]     = ot[0][t4];
            redA[rbase + 4 + t4] = ot[1][t4];
            redB[rbase + t4]     = ot[2][t4];
            redB[rbase + 4 + t4] = ot[3][t4];
        }
        redA[rbase + 8] = (f32x4){ol[0][0], ol[1][0], ol[2][0], ol[3][0]};
    }
    __syncthreads();
    if (!kw) {
        f32x4 olp = redA[rbase + 8];
        #pragma unroll
        for (int mt = 0; mt < 4; ++mt) {
            float inv = 1.0f / (ol[mt][0] + olp[mt]);
            #pragma unroll
            for (int t4 = 0; t4 < 4; ++t4) {
                f32x4 r = (mt < 2) ? redA[rbase + mt*4 + t4]
                                   : redB[rbase + (mt-2)*4 + t4];
                f32x4 o = ot[mt][t4] + r;
                ushort4 o4;
                o4.x = f2bf(o[0] * inv);
                o4.y = f2bf(o[1] * inv);
                o4.z = f2bf(o[2] * inv);
                o4.w = f2bf(o[3] * inv);
                *(ushort4*)(out + (size_t)(b*SEQ + qn0 + mt*16 + col)*DIM + h*HD + t4*16 + quad*4) = o4;
            }
        }
    }
}

extern "C" void kernel_launch(void* const* d_in, const int* in_sizes, int n_in,
                              void* d_out, int out_size, void* d_ws, size_t ws_size,
                              hipStream_t stream)
{
    (void)in_sizes; (void)n_in; (void)out_size; (void)ws_size;
    const float* x   = (const float*)d_in[0];
    const float* Wq  = (const float*)d_in[1];
    const float* Wk  = (const float*)d_in[2];
    const float* Wv  = (const float*)d_in[3];
    const float* Wo  = (const float*)d_in[4];
    const float* bo  = (const float*)d_in[5];
    const float* W1  = (const float*)d_in[6];
    const float* b1  = (const float*)d_in[7];
    const float* W2  = (const float*)d_in[8];
    const float* b2  = (const float*)d_in[9];
    const float* g1  = (const float*)d_in[10];
    const float* be1 = (const float*)d_in[11];
    const float* g2  = (const float*)d_in[12];
    const float* be2 = (const float*)d_in[13];

    // workspace layout (ushort units)
    ushort* u = (ushort*)d_ws;
    float*  x2    = (float*)u;                       // [0, 2SZ) ushorts = SZ floats
    ushort* h     = u + 2*(size_t)SZ;                // [2SZ, 3SZ)
    ushort* qb    = u + 3*(size_t)SZ;                // [3SZ, 4SZ)
    ushort* kb    = u + 4*(size_t)SZ;
    ushort* vb    = u + 5*(size_t)SZ;
    ushort* vtb   = u + 6*(size_t)SZ;
    ushort* attnb = u + 7*(size_t)SZ;                // [7SZ, 8SZ)
    ushort* ff1   = u + 3*(size_t)SZ;                // overlays qb..vtb (dead by then), 4SZ
    ushort* wqkv  = u + 8*(size_t)SZ;                // 4x 512*512 (q,k,v,o)
    ushort* wto   = wqkv + 3*(size_t)512*512;
    ushort* wt1   = wqkv + 4*(size_t)512*512;        // [2048][512]
    ushort* wt2   = wt1  + (size_t)512*2048;         // [512][2048]
    float*  outp  = (float*)d_out;

    // weights -> bf16 transposed [N][K]
    wtrans4_kernel<<<dim3(8,8,4), 256, 0, stream>>>(Wq, Wk, Wv, Wo, wqkv);
    wtrans_kernel<<<dim3(32,8), 256, 0, stream>>>(W1, wt1, 512, 2048);
    wtrans_kernel<<<dim3(8,32), 256, 0, stream>>>(W2, wt2, 2048, 512);

    // h = LN(x) -> bf16
    ln_kernel<<<ROWS, 128, 0, stream>>>(x, g1, be1, h);
    // q,k,v = h @ {Wq,Wk,Wv} -> bf16 (q scaled by 0.125*log2e)  [R11 config]
    gemm_bf16_kernel<128,256><<<dim3(1536/64, ROWS/128), 256, 0, stream>>>(
        h, wqkv, wqkv + (size_t)512*512, wqkv + 2*(size_t)512*512,
        nullptr, nullptr, qb, ROWS, 1536, DIM, 1);
    // vt = permuted transpose(v)
    vtrans_kernel<<<dim3(SEQ/64, BB*NH), 256, 0, stream>>>(vb, vtb);
    // attn = flash(q,k,v) -> bf16
    attn_mfma_kernel<<<dim3(SEQ/128, BB*NH), 256, 0, stream>>>(qb, kb, vtb, attnb);
    // x2 = x + attn @ Wo + bo  (fp32)
    gemm_bf16_kernel<64,128><<<dim3(DIM/64, ROWS/64), 128, 0, stream>>>(
        attnb, wto, wto, wto, bo, x, x2, ROWS, DIM, DIM, 8|4);
    // h = LN(x2) -> bf16
    ln_kernel<<<ROWS, 128, 0, stream>>>(x2, g2, be2, h);
    // ff1 = gelu(h @ W1 + b1) -> bf16  [R11 config]
    gemm_bf16_kernel<128,256><<<dim3(MLPD/64, ROWS/128), 256, 0, stream>>>(
        h, wt1, wt1, wt1, b1, nullptr, ff1, ROWS, MLPD, DIM, 8|2|16);
    // out = x2 + ff1 @ W2 + b2  (fp32)
    gemm_bf16_kernel<64,128><<<dim3(DIM/64, ROWS/64), 128, 0, stream>>>(
        ff1, wt2, wt2, wt2, b2, x2, outp, ROWS, DIM, MLPD, 8|4);
}

// Round 6
// 337.948 us; speedup vs baseline: 1.1921x; 1.0354x over previous
//
#include <hip/hip_runtime.h>
#include <math.h>

#define BB   2
#define SEQ  4096
#define DIM  512
#define NH   8
#define HD   64
#define MLPD 2048
#define ROWS (BB*SEQ)          /* 8192 */
#define SZ   (ROWS*DIM)        /* 4194304 elements */
#define EPSV 1e-5f

typedef __attribute__((ext_vector_type(8))) short bf16x8;   // A/B frag: 8 bf16
typedef __attribute__((ext_vector_type(4))) float f32x4;    // C/D frag: 4 f32

#if __has_builtin(__builtin_amdgcn_exp2f)
#define EXP2(x) __builtin_amdgcn_exp2f(x)
#else
#define EXP2(x) exp2f(x)
#endif

__device__ __forceinline__ ushort f2bf(float f) {           // RNE float->bf16
    unsigned u = __float_as_uint(f);
    u += 0x7fffu + ((u >> 16) & 1u);
    return (ushort)(u >> 16);
}
__device__ __forceinline__ unsigned pack2bf(float a, float b) {  // RNE [b:a]
    return (unsigned)f2bf(a) | ((unsigned)f2bf(b) << 16);
}
__device__ __forceinline__ unsigned pack2bf_tr(float a, float b) { // trunc [b:a], 1 op
    return (__float_as_uint(a) >> 16) | (__float_as_uint(b) & 0xffff0000u);
}

__device__ __forceinline__ void gload16(const ushort* g, ushort* l) {
    __builtin_amdgcn_global_load_lds(
        (const __attribute__((address_space(1))) unsigned*)g,
        (__attribute__((address_space(3))) unsigned*)l, 16, 0, 0);
}

// ---------------- LayerNorm -> bf16 (one block = one row of 512) ----------------
__global__ __launch_bounds__(128) void ln_kernel(const float* __restrict__ x,
        const float* __restrict__ g, const float* __restrict__ be,
        ushort* __restrict__ out)
{
    int row = blockIdx.x;
    int tid = threadIdx.x;
    const float4 v = ((const float4*)(x + (size_t)row*DIM))[tid];
    float s  = v.x + v.y + v.z + v.w;
    float ss = v.x*v.x + v.y*v.y + v.z*v.z + v.w*v.w;
    #pragma unroll
    for (int off = 32; off > 0; off >>= 1) {
        s  += __shfl_down(s,  off);
        ss += __shfl_down(ss, off);
    }
    __shared__ float red[4];
    if ((tid & 63) == 0) { red[(tid>>6)*2+0] = s; red[(tid>>6)*2+1] = ss; }
    __syncthreads();
    float sum = red[0] + red[2], sumsq = red[1] + red[3];
    float mu  = sum * (1.0f/DIM);
    float var = sumsq * (1.0f/DIM) - mu*mu;
    float rs  = rsqrtf(var + EPSV);
    float4 gv = ((const float4*)g)[tid];
    float4 bv = ((const float4*)be)[tid];
    ushort4 o;
    o.x = f2bf((v.x - mu)*rs*gv.x + bv.x);
    o.y = f2bf((v.y - mu)*rs*gv.y + bv.y);
    o.z = f2bf((v.z - mu)*rs*gv.z + bv.z);
    o.w = f2bf((v.w - mu)*rs*gv.w + bv.w);
    ((ushort4*)(out + (size_t)row*DIM))[tid] = o;
}

// ---------------- Weight transpose-convert: fp32 [K][N] -> bf16 [N][K] ----------------
__global__ __launch_bounds__(256) void wtrans_kernel(const float* __restrict__ W,
        ushort* __restrict__ Wt, int K, int N)
{
    __shared__ ushort T[64][65];
    int n0 = blockIdx.x*64, k0 = blockIdx.y*64;
    int tid = threadIdx.x;
    #pragma unroll
    for (int p = 0; p < 4; ++p) {
        int r = p*16 + (tid>>4), c = (tid&15)<<2;
        float4 w4 = *(const float4*)(W + (size_t)(k0+r)*N + n0 + c);
        T[c+0][r] = f2bf(w4.x); T[c+1][r] = f2bf(w4.y);
        T[c+2][r] = f2bf(w4.z); T[c+3][r] = f2bf(w4.w);
    }
    __syncthreads();
    #pragma unroll
    for (int p = 0; p < 4; ++p) {
        int n = p*16 + (tid>>4), k = (tid&15)<<2;
        ushort4 o; o.x = T[n][k]; o.y = T[n][k+1]; o.z = T[n][k+2]; o.w = T[n][k+3];
        *(ushort4*)(Wt + (size_t)(n0+n)*K + k0 + k) = o;
    }
}

// 4x 512x512 weights in one launch (z selects)
__global__ __launch_bounds__(256) void wtrans4_kernel(
        const float* __restrict__ W0, const float* __restrict__ W1,
        const float* __restrict__ W2, const float* __restrict__ W3,
        ushort* __restrict__ Wt)
{
    __shared__ ushort T[64][65];
    int z = blockIdx.z;
    const float* W = (z==0) ? W0 : (z==1) ? W1 : (z==2) ? W2 : W3;
    ushort* Wtz = Wt + (size_t)z*512*512;
    int n0 = blockIdx.x*64, k0 = blockIdx.y*64;
    int tid = threadIdx.x;
    #pragma unroll
    for (int p = 0; p < 4; ++p) {
        int r = p*16 + (tid>>4), c = (tid&15)<<2;
        float4 w4 = *(const float4*)(W + (size_t)(k0+r)*512 + n0 + c);
        T[c+0][r] = f2bf(w4.x); T[c+1][r] = f2bf(w4.y);
        T[c+2][r] = f2bf(w4.z); T[c+3][r] = f2bf(w4.w);
    }
    __syncthreads();
    #pragma unroll
    for (int p = 0; p < 4; ++p) {
        int n = p*16 + (tid>>4), k = (tid&15)<<2;
        ushort4 o; o.x = T[n][k]; o.y = T[n][k+1]; o.z = T[n][k+2]; o.w = T[n][k+3];
        *(ushort4*)(Wtz + (size_t)(n0+n)*512 + k0 + k) = o;
    }
}

// ---------------- bf16 MFMA GEMM, BN=64, BK=32, double-buffered ----------------
// R18: + XCD-aware block swizzle. BN=64 tiles re-read A ~(N/64)x and B ~(M/BM)x
// (1.3 GB/iteration across the 4 GEMMs); with default round-robin dispatch every
// A-panel streams from L3 (~6.5 TB/s => ~200us GEMM-aggregate). Swizzle gives
// each XCD a contiguous (by,bx) chunk, bx fastest: A-panel (<=1MB) + B weights
// (<=2MB) stay L2-resident per XCD. Requires nwg%8==0 (all grids comply;
// identity fallback otherwise). flags: 1=QKV-split 2=GELU 4=+resid 8=+bias 16=bf16 out
template<int BM, int NT>
__global__ __launch_bounds__(NT) void gemm_bf16_kernel(
        const ushort* __restrict__ A,
        const ushort* __restrict__ Wta, const ushort* __restrict__ Wtb, const ushort* __restrict__ Wtc,
        const float* __restrict__ bias, const float* __restrict__ resid,
        void* __restrict__ outv, int M, int Nn, int K, int flags)
{
    constexpr int AISS = (BM*4)/NT;      // A-tile DMA issues
    constexpr int BISS = 256/NT;         // B-tile DMA issues
    __shared__ ushort As[2][BM*32];
    __shared__ ushort Bs[2][64*32];
    int tid = threadIdx.x;
    int w = tid >> 6, lane = tid & 63, quad = lane >> 4, col = lane & 15;

    // XCD-aware swizzle: per-XCD contiguous chunk, bx fastest (A-panel reuse).
    int nx = gridDim.x;
    int nwg = nx * gridDim.y;
    int flat = blockIdx.x + nx * blockIdx.y;
    int bx, by;
    if ((nwg & 7) == 0) {
        int cpx = nwg >> 3;
        int slot = (flat & 7) * cpx + (flat >> 3);   // dispatch round-robins %8
        bx = slot % nx; by = slot / nx;
    } else { bx = blockIdx.x; by = blockIdx.y; }
    int row0 = by * BM, col0 = bx * 64;
    int wm0 = w * 32;

    const ushort* Wt; int wcol0, ostride, obase_col;
    float qscale = 1.0f;
    float* outF = nullptr; ushort* outB = nullptr;
    if (flags & 1) {
        int sel = col0 >> 9;
        Wt = (sel == 0) ? Wta : ((sel == 1) ? Wtb : Wtc);
        wcol0 = col0 & 511; ostride = 512; obase_col = wcol0;
        outB = (ushort*)outv + (size_t)sel * ((size_t)M * 512);
        if (sel == 0) qscale = 0.125f * 1.44269504088896f;  // 1/sqrt(HD) * log2(e)
        flags |= 16;
    } else {
        Wt = Wta; wcol0 = col0; ostride = Nn; obase_col = col0;
        if (flags & 16) outB = (ushort*)outv; else outF = (float*)outv;
    }

    f32x4 acc[2][4];
    #pragma unroll
    for (int i = 0; i < 2; ++i)
        #pragma unroll
        for (int j = 0; j < 4; ++j) acc[i][j] = (f32x4){0.f,0.f,0.f,0.f};

    const ushort* Ag = A  + (size_t)(row0  + (tid >> 2))*K + ((tid & 3) << 3);
    const ushort* Bg = Wt + (size_t)(wcol0 + (tid >> 2))*K + ((tid & 3) << 3);

    auto issue = [&](ushort* Ad, ushort* Bd, int ko) {
        #pragma unroll
        for (int it = 0; it < AISS; ++it)
            gload16(Ag + ko + (size_t)(it*(NT/4))*K, Ad + it*NT*8 + tid*8);
        #pragma unroll
        for (int it = 0; it < BISS; ++it)
            gload16(Bg + ko + (size_t)(it*(NT/4))*K, Bd + it*NT*8 + tid*8);
    };
    auto compute = [&](const ushort* Ab, const ushort* Bb) {
        bf16x8 af[2], bfr[4];
        #pragma unroll
        for (int i = 0; i < 2; ++i)
            af[i] = *(const bf16x8*)(Ab + (wm0 + i*16 + col)*32 + quad*8);
        #pragma unroll
        for (int j = 0; j < 4; ++j)
            bfr[j] = *(const bf16x8*)(Bb + (j*16 + col)*32 + quad*8);
        #pragma unroll
        for (int i = 0; i < 2; ++i)
            #pragma unroll
            for (int j = 0; j < 4; ++j)
                acc[i][j] = __builtin_amdgcn_mfma_f32_16x16x32_bf16(af[i], bfr[j], acc[i][j], 0, 0, 0);
    };

    int niter = K >> 5;                 // K/32, always even here
    issue(As[0], Bs[0], 0);
    for (int i = 0; i < niter; i += 2) {
        __syncthreads();                              // publish buf0 (DMA drained)
        if (i + 1 < niter) issue(As[1], Bs[1], (i+1)*32);   // prefetch overlaps compute
        compute(As[0], Bs[0]);
        __syncthreads();                              // publish buf1
        if (i + 2 < niter) issue(As[0], Bs[0], (i+2)*32);
        compute(As[1], Bs[1]);
    }

    #pragma unroll
    for (int i = 0; i < 2; ++i) {
        #pragma unroll
        for (int r = 0; r < 4; ++r) {
            int row = row0 + wm0 + i*16 + quad*4 + r;
            #pragma unroll
            for (int j = 0; j < 4; ++j) {
                int oc = obase_col + j*16 + col;
                float o = acc[i][j][r] * qscale;
                if (flags & 8) o += bias[oc];
                if (flags & 2) o = 0.5f*o*(1.f + erff(o*0.70710678118654752f));
                if (flags & 4) o += resid[(size_t)row*ostride + oc];
                if (flags & 16) outB[(size_t)row*ostride + oc] = f2bf(o);
                else            outF[(size_t)row*ostride + oc] = o;
            }
        }
    }
}

// ---------------- V transpose with PV-operand key permutation ----------------
// korig = ((key'>>5)*2 + ((key'>>2)&1))*16 + ((key'>>3)&3)*4 + (key'&3).
__global__ __launch_bounds__(256) void vtrans_kernel(const ushort* __restrict__ v,
                                                     ushort* __restrict__ vt)
{
    int tt = blockIdx.x, bh = blockIdx.y;
    int b = bh >> 3, h = bh & 7;
    int tid = threadIdx.x;
    int d = tid >> 2, t0 = (tid & 3) << 4;
    ushort tmp[16];
    #pragma unroll
    for (int i = 0; i < 16; ++i) {
        int kp = t0 + i;
        int korig = ((kp>>5)*2 + ((kp>>2)&1))*16 + ((kp>>3)&3)*4 + (kp&3);
        tmp[i] = v[(size_t)(b*SEQ + tt*64 + korig)*DIM + h*HD + d];
    }
    unsigned u[8];
    #pragma unroll
    for (int j = 0; j < 8; ++j) u[j] = (unsigned)tmp[2*j] | ((unsigned)tmp[2*j+1] << 16);
    ushort* dst = vt + ((size_t)bh*HD + d)*SEQ + tt*64 + t0;
    *(uint4*)(dst)     = make_uint4(u[0],u[1],u[2],u[3]);
    *(uint4*)(dst + 8) = make_uint4(u[4],u[5],u[6],u[7]);
}

// ---------------- MFMA flash attention: LDS-staged + XCD swizzle (R17) ----------------
__global__ __launch_bounds__(256, 2) void attn_mfma_kernel(
        const ushort* __restrict__ q, const ushort* __restrict__ k,
        const ushort* __restrict__ vt, ushort* __restrict__ out)
{
    __shared__ __align__(16) ushort Kt[2][64][72];
    __shared__ __align__(16) ushort Vt[2][64][72];

    // XCD-aware swizzle (R16-proven): each XCD serves only bh {2i,2i+1}.
    int flat = blockIdx.x + (blockIdx.y << 5);     // gridDim = (32, 16)
    int xcd  = flat & 7, slot = flat >> 3;         // dispatch round-robins % 8
    int bh   = (xcd << 1) | (slot >> 5);
    int qt   = slot & 31;
    int b = bh >> 3, h = bh & 7;
    int tid = threadIdx.x;
    int w = tid >> 6, lane = tid & 63;
    int quad = lane >> 4, col = lane & 15;
    int qw = w >> 1, kw = w & 1;            // pair: same q-rows, key halves
    int qn0 = qt*128 + qw*64;
    int krow0 = kw << 5;                    // this wave's 32 key rows in tile

    bf16x8 aq[4][2];    // Q^T B-operand, resident (64 q-rows per wave)
    #pragma unroll
    for (int mt = 0; mt < 4; ++mt) {
        const ushort* qp = q + (size_t)(b*SEQ + qn0 + mt*16 + col)*DIM + h*HD + quad*8;
        aq[mt][0] = *(const bf16x8*)(qp);
        aq[mt][1] = *(const bf16x8*)(qp + 32);
    }
    const short one_bf = (short)0x3F80;
    const bf16x8 ones = {one_bf,one_bf,one_bf,one_bf,one_bf,one_bf,one_bf,one_bf};
    const f32x4 zf = {0.f,0.f,0.f,0.f};

    f32x4 ot[4][4];
    f32x4 ol[4];
    #pragma unroll
    for (int mt = 0; mt < 4; ++mt) {
        ol[mt] = zf;
        #pragma unroll
        for (int t4 = 0; t4 < 4; ++t4) ot[mt][t4] = zf;
    }

    int skey = tid >> 2, sd0 = (tid & 3) << 4;
    bf16x8 kr[2], vr[2];
    auto load_tile = [&](int t) {
        const ushort* kp = k + (size_t)(b*SEQ + t*64 + skey)*DIM + h*HD + sd0;
        kr[0] = *(const bf16x8*)(kp);
        kr[1] = *(const bf16x8*)(kp + 8);
        const ushort* vp = vt + ((size_t)bh*HD + skey)*SEQ + t*64 + sd0;
        vr[0] = *(const bf16x8*)(vp);
        vr[1] = *(const bf16x8*)(vp + 8);
    };
    auto store_tile = [&](int p) {
        *(bf16x8*)&Kt[p][skey][sd0]     = kr[0];
        *(bf16x8*)&Kt[p][skey][sd0+8]   = kr[1];
        *(bf16x8*)&Vt[p][skey][sd0]     = vr[0];
        *(bf16x8*)&Vt[p][skey][sd0+8]   = vr[1];
    };

    load_tile(0);
    store_tile(0);
    __syncthreads();

    for (int t = 0; t < SEQ/64; ++t) {
        int p = t & 1;
        if (t + 1 < SEQ/64) load_tile(t + 1);     // VMEM in flight over compute

        // hoist ALL LDS fragment reads: kf feeds QK now, vf retires under QK/exp2
        bf16x8 kf0[2], kf1[2], vf[4];
        #pragma unroll
        for (int kb = 0; kb < 2; ++kb) {
            const ushort* kbp = &Kt[p][krow0 + kb*16 + col][quad*8];
            kf0[kb] = *(const bf16x8*)(kbp);
            kf1[kb] = *(const bf16x8*)(kbp + 32);
        }
        #pragma unroll
        for (int t4 = 0; t4 < 4; ++t4)
            vf[t4] = *(const bf16x8*)&Vt[p][t4*16 + col][krow0 + quad*8];

        // S^T = K Q^T (this wave's 32 keys x 64 q)
        f32x4 sc[4][2];
        __builtin_amdgcn_s_setprio(1);
        #pragma unroll
        for (int mt = 0; mt < 4; ++mt)
            #pragma unroll
            for (int kb = 0; kb < 2; ++kb) {
                sc[mt][kb] = __builtin_amdgcn_mfma_f32_16x16x32_bf16(kf0[kb], aq[mt][0], zf, 0, 0, 0);
                sc[mt][kb] = __builtin_amdgcn_mfma_f32_16x16x32_bf16(kf1[kb], aq[mt][1], sc[mt][kb], 0, 0, 0);
            }
        __builtin_amdgcn_s_setprio(0);

        // P^T = exp2(S^T), in-register repack (truncating, 1 op per pair)
        union PU { bf16x8 v; uint4 u; };
        PU pb[4];
        #pragma unroll
        for (int mt = 0; mt < 4; ++mt) {
            pb[mt].u.x = pack2bf_tr(EXP2(sc[mt][0][0]), EXP2(sc[mt][0][1]));
            pb[mt].u.y = pack2bf_tr(EXP2(sc[mt][0][2]), EXP2(sc[mt][0][3]));
            pb[mt].u.z = pack2bf_tr(EXP2(sc[mt][1][0]), EXP2(sc[mt][1][1]));
            pb[mt].u.w = pack2bf_tr(EXP2(sc[mt][1][2]), EXP2(sc[mt][1][3]));
        }

        // O^T += V^T P^T over this wave's key chunk ; l += 1 P^T
        __builtin_amdgcn_s_setprio(1);
        #pragma unroll
        for (int mt = 0; mt < 4; ++mt) {
            #pragma unroll
            for (int t4 = 0; t4 < 4; ++t4)
                ot[mt][t4] = __builtin_amdgcn_mfma_f32_16x16x32_bf16(vf[t4], pb[mt].v, ot[mt][t4], 0, 0, 0);
            ol[mt] = __builtin_amdgcn_mfma_f32_16x16x32_bf16(ones, pb[mt].v, ol[mt], 0, 0, 0);
        }
        __builtin_amdgcn_s_setprio(0);

        if (t + 1 < SEQ/64) store_tile(p ^ 1);    // tile t-1 fully consumed pre-barrier
        __syncthreads();
    }

    // cross-wave (key-half) reduction through the dead K/V buffers.
    // stride 9 f32x4 = 36 words -> bank-group (lane + i) & 7, uniform.
    f32x4* redA = (f32x4*)Kt;   // 1152 slots: ot[0][*], ot[1][*], packed l
    f32x4* redB = (f32x4*)Vt;   // stride 9 too: ot[2][*], ot[3][*]
    int rbase = ((qw << 6) + lane) * 9;
    if (kw) {
        #pragma unroll
        for (int t4 = 0; t4 < 4; ++t4) {
            redA[rbase + t4]     = ot[0][t4];
            redA[rbase + 4 + t4] = ot[1][t4];
            redB[rbase + t4]     = ot[2][t4];
            redB[rbase + 4 + t4] = ot[3][t4];
        }
        redA[rbase + 8] = (f32x4){ol[0][0], ol[1][0], ol[2][0], ol[3][0]};
    }
    __syncthreads();
    if (!kw) {
        f32x4 olp = redA[rbase + 8];
        #pragma unroll
        for (int mt = 0; mt < 4; ++mt) {
            float inv = 1.0f / (ol[mt][0] + olp[mt]);
            #pragma unroll
            for (int t4 = 0; t4 < 4; ++t4) {
                f32x4 r = (mt < 2) ? redA[rbase + mt*4 + t4]
                                   : redB[rbase + (mt-2)*4 + t4];
                f32x4 o = ot[mt][t4] + r;
                ushort4 o4;
                o4.x = f2bf(o[0] * inv);
                o4.y = f2bf(o[1] * inv);
                o4.z = f2bf(o[2] * inv);
                o4.w = f2bf(o[3] * inv);
                *(ushort4*)(out + (size_t)(b*SEQ + qn0 + mt*16 + col)*DIM + h*HD + t4*16 + quad*4) = o4;
            }
        }
    }
}

extern "C" void kernel_launch(void* const* d_in, const int* in_sizes, int n_in,
                              void* d_out, int out_size, void* d_ws, size_t ws_size,
                              hipStream_t stream)
{
    (void)in_sizes; (void)n_in; (void)out_size; (void)ws_size;
    const float* x   = (const float*)d_in[0];
    const float* Wq  = (const float*)d_in[1];
    const float* Wk  = (const float*)d_in[2];
    const float* Wv  = (const float*)d_in[3];
    const float* Wo  = (const float*)d_in[4];
    const float* bo  = (const float*)d_in[5];
    const float* W1  = (const float*)d_in[6];
    const float* b1  = (const float*)d_in[7];
    const float* W2  = (const float*)d_in[8];
    const float* b2  = (const float*)d_in[9];
    const float* g1  = (const float*)d_in[10];
    const float* be1 = (const float*)d_in[11];
    const float* g2  = (const float*)d_in[12];
    const float* be2 = (const float*)d_in[13];

    // workspace layout (ushort units)
    ushort* u = (ushort*)d_ws;
    float*  x2    = (float*)u;                       // [0, 2SZ) ushorts = SZ floats
    ushort* h     = u + 2*(size_t)SZ;                // [2SZ, 3SZ)
    ushort* qb    = u + 3*(size_t)SZ;                // [3SZ, 4SZ)
    ushort* kb    = u + 4*(size_t)SZ;
    ushort* vb    = u + 5*(size_t)SZ;
    ushort* vtb   = u + 6*(size_t)SZ;
    ushort* attnb = u + 7*(size_t)SZ;                // [7SZ, 8SZ)
    ushort* ff1   = u + 3*(size_t)SZ;                // overlays qb..vtb (dead by then), 4SZ
    ushort* wqkv  = u + 8*(size_t)SZ;                // 4x 512*512 (q,k,v,o)
    ushort* wto   = wqkv + 3*(size_t)512*512;
    ushort* wt1   = wqkv + 4*(size_t)512*512;        // [2048][512]
    ushort* wt2   = wt1  + (size_t)512*2048;         // [512][2048]
    float*  outp  = (float*)d_out;

    // weights -> bf16 transposed [N][K]
    wtrans4_kernel<<<dim3(8,8,4), 256, 0, stream>>>(Wq, Wk, Wv, Wo, wqkv);
    wtrans_kernel<<<dim3(32,8), 256, 0, stream>>>(W1, wt1, 512, 2048);
    wtrans_kernel<<<dim3(8,32), 256, 0, stream>>>(W2, wt2, 2048, 512);

    // h = LN(x) -> bf16
    ln_kernel<<<ROWS, 128, 0, stream>>>(x, g1, be1, h);
    // q,k,v = h @ {Wq,Wk,Wv} -> bf16 (q scaled by 0.125*log2e)  [R11 config]
    gemm_bf16_kernel<128,256><<<dim3(1536/64, ROWS/128), 256, 0, stream>>>(
        h, wqkv, wqkv + (size_t)512*512, wqkv + 2*(size_t)512*512,
        nullptr, nullptr, qb, ROWS, 1536, DIM, 1);
    // vt = permuted transpose(v)
    vtrans_kernel<<<dim3(SEQ/64, BB*NH), 256, 0, stream>>>(vb, vtb);
    // attn = flash(q,k,v) -> bf16
    attn_mfma_kernel<<<dim3(SEQ/128, BB*NH), 256, 0, stream>>>(qb, kb, vtb, attnb);
    // x2 = x + attn @ Wo + bo  (fp32)
    gemm_bf16_kernel<64,128><<<dim3(DIM/64, ROWS/64), 128, 0, stream>>>(
        attnb, wto, wto, wto, bo, x, x2, ROWS, DIM, DIM, 8|4);
    // h = LN(x2) -> bf16
    ln_kernel<<<ROWS, 128, 0, stream>>>(x2, g2, be2, h);
    // ff1 = gelu(h @ W1 + b1) -> bf16  [R11 config]
    gemm_bf16_kernel<128,256><<<dim3(MLPD/64, ROWS/128), 256, 0, stream>>>(
        h, wt1, wt1, wt1, b1, nullptr, ff1, ROWS, MLPD, DIM, 8|2|16);
    // out = x2 + ff1 @ W2 + b2  (fp32)
    gemm_bf16_kernel<64,128><<<dim3(DIM/64, ROWS/64), 128, 0, stream>>>(
        ff1, wt2, wt2, wt2, b2, x2, outp, ROWS, DIM, MLPD, 8|4);
}